// Round 1
// baseline (1143.143 us; speedup 1.0000x reference)
//
#include <hip/hip_runtime.h>
#include <math.h>

#define L_SEQ 2048
#define BATCH 2
#define EMB 1024
#define NH 16
#define HDIM 64
#define F3 3072
#define NROWS 4096   // L_SEQ * BATCH

// ws layout (floats after a 256B slot header):
// slots[0]=absmax(in_w) [1]=absmax(out_w) [2]=absmax(X) [3]=absmax(Xq Q-region)
// [4]=absmax(heads) [5]=absmax(y)

__device__ __forceinline__ float fqv(float x, float s) {
  return rintf(fminf(fmaxf(x / s, -128.0f), 127.0f)) * s;
}
__device__ __forceinline__ float load_scale(const unsigned* slots, int i, float premul) {
  return fmaxf(__uint_as_float(slots[i]) * premul / 127.0f, 1e-8f);
}

__device__ __forceinline__ void blockmax_commit(float m, unsigned* slot) {
  #pragma unroll
  for (int o = 1; o < 64; o <<= 1) m = fmaxf(m, __shfl_xor(m, o));
  __shared__ float sm[4];
  if ((threadIdx.x & 63) == 0) sm[threadIdx.x >> 6] = m;
  __syncthreads();
  if (threadIdx.x == 0) {
    float mm = fmaxf(fmaxf(sm[0], sm[1]), fmaxf(sm[2], sm[3]));
    atomicMax(slot, __float_as_uint(mm));
  }
}

__global__ __launch_bounds__(256) void absmax_k(const float* __restrict__ x, int n4,
                                                unsigned* __restrict__ slot) {
  const float4* x4 = (const float4*)x;
  float m = 0.0f;
  for (int i = blockIdx.x * blockDim.x + threadIdx.x; i < n4; i += gridDim.x * blockDim.x) {
    float4 v = x4[i];
    m = fmaxf(m, fmaxf(fmaxf(fabsf(v.x), fabsf(v.y)), fmaxf(fabsf(v.z), fabsf(v.w))));
  }
  blockmax_commit(m, slot);
}

// absmax over Q-region of X (cols 0..EMB-1 of each 3072-wide row)
__global__ __launch_bounds__(256) void absmax_qreg_k(const float* __restrict__ X,
                                                     unsigned* __restrict__ slot) {
  float m = 0.0f;
  const int total = NROWS * (EMB / 4);
  for (int i = blockIdx.x * blockDim.x + threadIdx.x; i < total; i += gridDim.x * blockDim.x) {
    int n = i >> 8;           // /(EMB/4)
    int c4 = i & 255;
    float4 v = *(const float4*)&X[(size_t)n * F3 + c4 * 4];
    m = fmaxf(m, fmaxf(fmaxf(fabsf(v.x), fabsf(v.y)), fmaxf(fabsf(v.z), fabsf(v.w))));
  }
  blockmax_commit(m, slot);
}

__global__ __launch_bounds__(256) void quant_k(const float* __restrict__ x,
                                               float* __restrict__ y, int n4,
                                               const unsigned* __restrict__ slots, int sloti) {
  float s = load_scale(slots, sloti, 1.0f);
  const float4* x4 = (const float4*)x;
  float4* y4 = (float4*)y;
  for (int i = blockIdx.x * blockDim.x + threadIdx.x; i < n4; i += gridDim.x * blockDim.x) {
    float4 v = x4[i];
    v.x = fqv(v.x, s); v.y = fqv(v.y, s); v.z = fqv(v.z, s); v.w = fqv(v.w, s);
    y4[i] = v;
  }
}

// in-place: Q-region of X: q = xq/8, then fake-quant with scale from slots[3]/8
__global__ __launch_bounds__(256) void quant_qreg_k(float* __restrict__ X,
                                                    const unsigned* __restrict__ slots) {
  float s = load_scale(slots, 3, 0.125f);
  const int total = NROWS * (EMB / 4);
  for (int i = blockIdx.x * blockDim.x + threadIdx.x; i < total; i += gridDim.x * blockDim.x) {
    int n = i >> 8;
    int c4 = i & 255;
    float4* p = (float4*)&X[(size_t)n * F3 + c4 * 4];
    float4 v = *p;
    v.x = fqv(v.x * 0.125f, s); v.y = fqv(v.y * 0.125f, s);
    v.z = fqv(v.z * 0.125f, s); v.w = fqv(v.w * 0.125f, s);
    *p = v;
  }
}

// C[M,N] = A[M,K] @ B[N,K]^T + bias[N]; M,N % 128 == 0, K % 16 == 0
__global__ __launch_bounds__(256) void gemm_bt_k(const float* __restrict__ A,
                                                 const float* __restrict__ Bm,
                                                 const float* __restrict__ bias,
                                                 float* __restrict__ C,
                                                 int M, int N, int K) {
  __shared__ float As[16][128];
  __shared__ float Bs[16][128];
  int t = threadIdx.x;
  int tx = t & 15, ty = t >> 4;
  int bm = blockIdx.y * 128, bn = blockIdx.x * 128;
  float acc[8][8] = {};
  for (int k0 = 0; k0 < K; k0 += 16) {
    __syncthreads();
    #pragma unroll
    for (int i = 0; i < 2; ++i) {
      int u = t + i * 256;              // 0..511
      int r = u >> 2, kq = u & 3;
      float4 v = *(const float4*)&A[(size_t)(bm + r) * K + k0 + kq * 4];
      As[kq * 4 + 0][r] = v.x; As[kq * 4 + 1][r] = v.y;
      As[kq * 4 + 2][r] = v.z; As[kq * 4 + 3][r] = v.w;
    }
    #pragma unroll
    for (int i = 0; i < 2; ++i) {
      int u = t + i * 256;
      int r = u >> 2, kq = u & 3;
      float4 v = *(const float4*)&Bm[(size_t)(bn + r) * K + k0 + kq * 4];
      Bs[kq * 4 + 0][r] = v.x; Bs[kq * 4 + 1][r] = v.y;
      Bs[kq * 4 + 2][r] = v.z; Bs[kq * 4 + 3][r] = v.w;
    }
    __syncthreads();
    #pragma unroll
    for (int kk = 0; kk < 16; ++kk) {
      float a[8], bb[8];
      *(float4*)&a[0]  = *(const float4*)&As[kk][ty * 8];
      *(float4*)&a[4]  = *(const float4*)&As[kk][ty * 8 + 4];
      *(float4*)&bb[0] = *(const float4*)&Bs[kk][tx * 8];
      *(float4*)&bb[4] = *(const float4*)&Bs[kk][tx * 8 + 4];
      #pragma unroll
      for (int i = 0; i < 8; ++i)
        #pragma unroll
        for (int j = 0; j < 8; ++j)
          acc[i][j] += a[i] * bb[j];
    }
  }
  #pragma unroll
  for (int i = 0; i < 8; ++i) {
    int r = bm + ty * 8 + i;
    #pragma unroll
    for (int j4 = 0; j4 < 2; ++j4) {
      int c = bn + tx * 8 + j4 * 4;
      float4 o;
      o.x = acc[i][j4 * 4 + 0] + bias[c + 0];
      o.y = acc[i][j4 * 4 + 1] + bias[c + 1];
      o.z = acc[i][j4 * 4 + 2] + bias[c + 2];
      o.w = acc[i][j4 * 4 + 3] + bias[c + 3];
      *(float4*)&C[(size_t)r * N + c] = o;
    }
  }
}

// Flash attention, fp32. X holds [n=l*B+b][f]: f<1024 -> q_fq, 1024..2047 -> k, 2048..3071 -> v.
// grid: (qb=32, bh=32), 256 threads. Output headsR[n][h*64+d].
__global__ __launch_bounds__(256) void attn_k(const float* __restrict__ X,
                                              float* __restrict__ headsR) {
  int qb = blockIdx.x;
  int bh = blockIdx.y;
  int b = bh >> 4, h = bh & 15;
  __shared__ float QsT[HDIM][68];   // [d][r]
  __shared__ float KVs[64][68];     // K as [d][c], later V as [c][d]
  __shared__ float Ss[64][65];
  __shared__ float fac[64];
  __shared__ float lrow[64];

  int t = threadIdx.x;
  int tx = t & 15, ty = t >> 4;
  int sr = t >> 2, sq = t & 3;      // softmax: row, quarter

  // load Q tile (transposed into QsT[d][r])
  #pragma unroll
  for (int k = 0; k < 4; ++k) {
    int u = t + k * 256;            // 0..1023
    int r = u >> 4, dq = u & 15;
    float4 v = *(const float4*)&X[((size_t)(qb * 64 + r) * BATCH + b) * F3 + h * HDIM + dq * 4];
    QsT[dq * 4 + 0][r] = v.x; QsT[dq * 4 + 1][r] = v.y;
    QsT[dq * 4 + 2][r] = v.z; QsT[dq * 4 + 3][r] = v.w;
  }

  float acc_o[4][4] = {};
  float m_prev = -INFINITY, lsum = 0.0f;

  for (int kt = 0; kt < L_SEQ / 64; ++kt) {
    __syncthreads();   // Q stores / previous PV reads complete
    // load K tile -> KVs[d][c]
    #pragma unroll
    for (int k = 0; k < 4; ++k) {
      int u = t + k * 256;
      int c = u >> 4, dq = u & 15;
      float4 v = *(const float4*)&X[((size_t)(kt * 64 + c) * BATCH + b) * F3 + EMB + h * HDIM + dq * 4];
      KVs[dq * 4 + 0][c] = v.x; KVs[dq * 4 + 1][c] = v.y;
      KVs[dq * 4 + 2][c] = v.z; KVs[dq * 4 + 3][c] = v.w;
    }
    __syncthreads();
    // S = Q @ K^T  (rows=q, cols=k)
    float accs[4][4] = {};
    #pragma unroll
    for (int d = 0; d < HDIM; ++d) {
      float a[4], bb[4];
      *(float4*)a  = *(const float4*)&QsT[d][ty * 4];
      *(float4*)bb = *(const float4*)&KVs[d][tx * 4];
      #pragma unroll
      for (int i = 0; i < 4; ++i)
        #pragma unroll
        for (int j = 0; j < 4; ++j)
          accs[i][j] += a[i] * bb[j];
    }
    #pragma unroll
    for (int i = 0; i < 4; ++i)
      #pragma unroll
      for (int j = 0; j < 4; ++j)
        Ss[ty * 4 + i][tx * 4 + j] = accs[i][j];
    __syncthreads();   // K reads done, S visible
    // online softmax (4 threads per row) + V load into KVs[c][d]
    {
      float vals[16];
      float pm = -INFINITY;
      #pragma unroll
      for (int cc = 0; cc < 16; ++cc) { vals[cc] = Ss[sr][sq * 16 + cc]; pm = fmaxf(pm, vals[cc]); }
      pm = fmaxf(pm, __shfl_xor(pm, 1));
      pm = fmaxf(pm, __shfl_xor(pm, 2));
      float mnew = fmaxf(m_prev, pm);
      float f = expf(m_prev - mnew);
      float ps = 0.0f;
      #pragma unroll
      for (int cc = 0; cc < 16; ++cc) {
        float p = expf(vals[cc] - mnew);
        Ss[sr][sq * 16 + cc] = p;
        ps += p;
      }
      ps += __shfl_xor(ps, 1);
      ps += __shfl_xor(ps, 2);
      lsum = lsum * f + ps;
      m_prev = mnew;
      if (sq == 0) fac[sr] = f;
    }
    #pragma unroll
    for (int k = 0; k < 4; ++k) {
      int u = t + k * 256;
      int c = u >> 4, dq = u & 15;
      float4 v = *(const float4*)&X[((size_t)(kt * 64 + c) * BATCH + b) * F3 + 2 * EMB + h * HDIM + dq * 4];
      *(float4*)&KVs[c][dq * 4] = v;
    }
    __syncthreads();   // P, fac, V visible
    // rescale O and accumulate P @ V
    #pragma unroll
    for (int i = 0; i < 4; ++i) {
      float f = fac[ty * 4 + i];
      #pragma unroll
      for (int j = 0; j < 4; ++j) acc_o[i][j] *= f;
    }
    #pragma unroll 4
    for (int c = 0; c < 64; ++c) {
      float a[4], bb[4];
      #pragma unroll
      for (int i = 0; i < 4; ++i) a[i] = Ss[ty * 4 + i][c];
      *(float4*)bb = *(const float4*)&KVs[c][tx * 4];
      #pragma unroll
      for (int i = 0; i < 4; ++i)
        #pragma unroll
        for (int j = 0; j < 4; ++j)
          acc_o[i][j] += a[i] * bb[j];
    }
  }
  if (sq == 0) lrow[sr] = lsum;
  __syncthreads();
  #pragma unroll
  for (int i = 0; i < 4; ++i) {
    int r = ty * 4 + i;
    float l = lrow[r];
    float4 o;
    o.x = acc_o[i][0] / l; o.y = acc_o[i][1] / l;
    o.z = acc_o[i][2] / l; o.w = acc_o[i][3] / l;
    *(float4*)&headsR[((size_t)(qb * 64 + r) * BATCH + b) * EMB + h * HDIM + tx * 4] = o;
  }
}

extern "C" void kernel_launch(void* const* d_in, const int* in_sizes, int n_in,
                              void* d_out, int out_size, void* d_ws, size_t ws_size,
                              hipStream_t stream) {
  (void)in_sizes; (void)n_in; (void)out_size; (void)ws_size;
  const float* query = (const float*)d_in[0];
  const float* in_w  = (const float*)d_in[3];
  const float* in_b  = (const float*)d_in[4];
  const float* out_w = (const float*)d_in[5];
  const float* out_b = (const float*)d_in[6];
  float* out = (float*)d_out;

  unsigned* slots = (unsigned*)d_ws;
  float* base = (float*)d_ws + 64;
  float* Wiq    = base;                          // 3072*1024
  float* Woq    = Wiq + (size_t)F3 * EMB;        // 1024*1024
  float* X      = Woq + (size_t)EMB * EMB;       // 4096*3072
  float* headsR = X + (size_t)NROWS * F3;        // 4096*1024

  hipMemsetAsync(d_ws, 0, 256, stream);

  dim3 b256(256);
  // weight fake-quant
  absmax_k<<<1024, b256, 0, stream>>>(in_w, F3 * EMB / 4, slots + 0);
  absmax_k<<<512,  b256, 0, stream>>>(out_w, EMB * EMB / 4, slots + 1);
  quant_k<<<1536, b256, 0, stream>>>(in_w, Wiq, F3 * EMB / 4, slots, 0);
  quant_k<<<512,  b256, 0, stream>>>(out_w, Woq, EMB * EMB / 4, slots, 1);

  // input projection + fake-quant of X
  gemm_bt_k<<<dim3(F3 / 128, NROWS / 128), b256, 0, stream>>>(query, Wiq, in_b, X, NROWS, F3, EMB);
  absmax_k<<<2048, b256, 0, stream>>>(X, NROWS * F3 / 4, slots + 2);
  quant_k<<<2048, b256, 0, stream>>>(X, X, NROWS * F3 / 4, slots, 2);

  // q = fq(Xq_Q / 8)
  absmax_qreg_k<<<1024, b256, 0, stream>>>(X, slots + 3);
  quant_qreg_k<<<1024, b256, 0, stream>>>(X, slots);

  // attention
  attn_k<<<dim3(L_SEQ / 64, BATCH * NH), b256, 0, stream>>>(X, headsR);

  // heads fake-quant
  absmax_k<<<1024, b256, 0, stream>>>(headsR, NROWS * EMB / 4, slots + 4);
  quant_k<<<1024, b256, 0, stream>>>(headsR, headsR, NROWS * EMB / 4, slots, 4);

  // output projection + final fake-quant (in place in d_out)
  gemm_bt_k<<<dim3(EMB / 128, NROWS / 128), b256, 0, stream>>>(headsR, Woq, out_b, out, NROWS, EMB, EMB);
  absmax_k<<<1024, b256, 0, stream>>>(out, NROWS * EMB / 4, slots + 5);
  quant_k<<<1024, b256, 0, stream>>>(out, out, NROWS * EMB / 4, slots, 5);
}

// Round 2
// 438.380 us; speedup vs baseline: 2.6077x; 2.6077x over previous
//
#include <hip/hip_runtime.h>
#include <math.h>

#define L_SEQ 2048
#define BATCH 2
#define EMB 1024
#define NH 16
#define HDIM 64
#define F3 3072
#define NROWS 4096   // L_SEQ * BATCH

typedef __bf16 bf16_t;
typedef short s16x8 __attribute__((ext_vector_type(8)));
typedef float f32x4 __attribute__((ext_vector_type(4)));

#define MFMA16(a, b, c) __builtin_amdgcn_mfma_f32_16x16x32_bf16(a, b, c, 0, 0, 0)

// ws slots (uint bits of fp32 absmax):
// [0]=absmax(in_w) [1]=absmax(out_w) [2]=absmax(X) [3]=max|int| of Xq Q-region
// [4]=absmax(heads) [5]=absmax(y)

__device__ __forceinline__ float u2f(unsigned u) { return __uint_as_float(u); }

__device__ __forceinline__ void blockmax_commit(float m, unsigned* slot) {
  #pragma unroll
  for (int o = 1; o < 64; o <<= 1) m = fmaxf(m, __shfl_xor(m, o));
  __shared__ float sm[4];
  if ((threadIdx.x & 63) == 0) sm[threadIdx.x >> 6] = m;
  __syncthreads();
  if (threadIdx.x == 0) {
    float mm = fmaxf(fmaxf(sm[0], sm[1]), fmaxf(sm[2], sm[3]));
    atomicMax(slot, __float_as_uint(mm));
  }
}

__global__ __launch_bounds__(256) void absmax_k(const float* __restrict__ x, int n4,
                                                unsigned* __restrict__ slot) {
  const float4* x4 = (const float4*)x;
  float m = 0.0f;
  for (int i = blockIdx.x * blockDim.x + threadIdx.x; i < n4; i += gridDim.x * blockDim.x) {
    float4 v = x4[i];
    m = fmaxf(m, fmaxf(fmaxf(fabsf(v.x), fabsf(v.y)), fmaxf(fabsf(v.z), fabsf(v.w))));
  }
  blockmax_commit(m, slot);
}

// fp32 -> integer-valued bf16 (n = rint(clip(x/s, -128, 127)))
__global__ __launch_bounds__(256) void quantf_k(const float* __restrict__ x,
                                                bf16_t* __restrict__ y, int n4,
                                                const unsigned* __restrict__ slots, int sloti) {
  float s = fmaxf(u2f(slots[sloti]) / 127.0f, 1e-8f);
  const float4* x4 = (const float4*)x;
  for (int i = blockIdx.x * blockDim.x + threadIdx.x; i < n4; i += gridDim.x * blockDim.x) {
    float4 v = x4[i];
    bf16_t o[4];
    o[0] = (bf16_t)rintf(fminf(fmaxf(v.x / s, -128.0f), 127.0f));
    o[1] = (bf16_t)rintf(fminf(fmaxf(v.y / s, -128.0f), 127.0f));
    o[2] = (bf16_t)rintf(fminf(fmaxf(v.z / s, -128.0f), 127.0f));
    o[3] = (bf16_t)rintf(fminf(fmaxf(v.w / s, -128.0f), 127.0f));
    *(uint2*)&y[(size_t)i * 4] = *(uint2*)o;
  }
}

// fp32 real-valued fake-quant in place (final output)
__global__ __launch_bounds__(256) void quant_k(float* __restrict__ x, int n4,
                                               const unsigned* __restrict__ slots, int sloti) {
  float s = fmaxf(u2f(slots[sloti]) / 127.0f, 1e-8f);
  float4* x4 = (float4*)x;
  for (int i = blockIdx.x * blockDim.x + threadIdx.x; i < n4; i += gridDim.x * blockDim.x) {
    float4 v = x4[i];
    v.x = rintf(fminf(fmaxf(v.x / s, -128.0f), 127.0f)) * s;
    v.y = rintf(fminf(fmaxf(v.y / s, -128.0f), 127.0f)) * s;
    v.z = rintf(fminf(fmaxf(v.z / s, -128.0f), 127.0f)) * s;
    v.w = rintf(fminf(fmaxf(v.w / s, -128.0f), 127.0f)) * s;
    x4[i] = v;
  }
}

// fp32 -> (hi, lo) bf16 pair
__global__ __launch_bounds__(256) void split_k(const float* __restrict__ x,
                                               bf16_t* __restrict__ hi,
                                               bf16_t* __restrict__ lo, int n4) {
  const float4* x4 = (const float4*)x;
  for (int i = blockIdx.x * blockDim.x + threadIdx.x; i < n4; i += gridDim.x * blockDim.x) {
    float4 v = x4[i];
    bf16_t h[4], l[4];
    float vv[4] = {v.x, v.y, v.z, v.w};
    #pragma unroll
    for (int j = 0; j < 4; ++j) {
      h[j] = (bf16_t)vv[j];
      l[j] = (bf16_t)(vv[j] - (float)h[j]);
    }
    *(uint2*)&hi[(size_t)i * 4] = *(uint2*)h;
    *(uint2*)&lo[(size_t)i * 4] = *(uint2*)l;
  }
}

// max |int| over Q-region (cols 0..1023) of X_int (bf16 ints)
__global__ __launch_bounds__(256) void absmax_bf16_qreg_k(const bf16_t* __restrict__ X,
                                                          unsigned* __restrict__ slot) {
  float m = 0.0f;
  const int total = NROWS * (EMB / 8);
  for (int i = blockIdx.x * blockDim.x + threadIdx.x; i < total; i += gridDim.x * blockDim.x) {
    int n = i >> 7, c = i & 127;
    const bf16_t* p = X + (size_t)n * F3 + c * 8;
    #pragma unroll
    for (int j = 0; j < 8; ++j) m = fmaxf(m, fabsf((float)p[j]));
  }
  blockmax_commit(m, slot);
}

// in-place requant of Q-region: n2 = rint(clip(((n*s_x)*0.125)/s_q, -128, 127))
__global__ __launch_bounds__(256) void requant_qreg_k(bf16_t* __restrict__ X,
                                                      const unsigned* __restrict__ slots) {
  float s_x = fmaxf(u2f(slots[2]) / 127.0f, 1e-8f);
  float s_q = fmaxf((u2f(slots[3]) * s_x) * 0.125f / 127.0f, 1e-8f);
  const int total = NROWS * (EMB / 8);
  for (int i = blockIdx.x * blockDim.x + threadIdx.x; i < total; i += gridDim.x * blockDim.x) {
    int n = i >> 7, c = i & 127;
    bf16_t* p = X + (size_t)n * F3 + c * 8;
    bf16_t v[8];
    *(uint4*)v = *(const uint4*)p;
    #pragma unroll
    for (int j = 0; j < 8; ++j) {
      float q = ((float)v[j] * s_x) * 0.125f;
      v[j] = (bf16_t)rintf(fminf(fmaxf(q / s_q, -128.0f), 127.0f));
    }
    *(uint4*)p = *(uint4*)v;
  }
}

// C[M,N] = (sum_p A_p[M,K]) @ B[N,K]^T * scale + bias[N]; bf16 in, f32 out.
// M,N % 128 == 0, K % 32 == 0. 256 thr, 4 waves in 2x2, each wave 64x64 out.
template <int NPARTS>
__global__ __launch_bounds__(256) void gemm_bt_mfma_k(const bf16_t* __restrict__ A0,
                                                      const bf16_t* __restrict__ A1,
                                                      const bf16_t* __restrict__ Bm,
                                                      const float* __restrict__ bias,
                                                      float* __restrict__ C,
                                                      int M, int N, int K,
                                                      const unsigned* __restrict__ slots,
                                                      int sa, int sb) {
  __shared__ __align__(16) bf16_t As[NPARTS][128][40];
  __shared__ __align__(16) bf16_t Bs[128][40];
  int t = threadIdx.x;
  int w = t >> 6, l = t & 63, c15 = l & 15, g = l >> 4;
  int wr = w >> 1, wc = w & 1;
  int bm = blockIdx.y * 128, bn = blockIdx.x * 128;
  f32x4 acc[4][4] = {};

  for (int k0 = 0; k0 < K; k0 += 32) {
    __syncthreads();
    #pragma unroll
    for (int i = 0; i < 2; ++i) {
      int s = t + i * 256;
      int row = s >> 2, seg = s & 3;
      *(uint4*)&As[0][row][seg * 8] = *(const uint4*)&A0[(size_t)(bm + row) * K + k0 + seg * 8];
      if (NPARTS == 2)
        *(uint4*)&As[1][row][seg * 8] = *(const uint4*)&A1[(size_t)(bm + row) * K + k0 + seg * 8];
      *(uint4*)&Bs[row][seg * 8] = *(const uint4*)&Bm[(size_t)(bn + row) * K + k0 + seg * 8];
    }
    __syncthreads();
    s16x8 af[NPARTS][4], bf_[4];
    #pragma unroll
    for (int rt = 0; rt < 4; ++rt) {
      af[0][rt] = *(const s16x8*)&As[0][wr * 64 + rt * 16 + c15][g * 8];
      if (NPARTS == 2) af[1][rt] = *(const s16x8*)&As[1][wr * 64 + rt * 16 + c15][g * 8];
    }
    #pragma unroll
    for (int ct = 0; ct < 4; ++ct)
      bf_[ct] = *(const s16x8*)&Bs[wc * 64 + ct * 16 + c15][g * 8];
    #pragma unroll
    for (int rt = 0; rt < 4; ++rt)
      #pragma unroll
      for (int ct = 0; ct < 4; ++ct) {
        acc[rt][ct] = MFMA16(af[0][rt], bf_[ct], acc[rt][ct]);
        if (NPARTS == 2) acc[rt][ct] = MFMA16(af[1][rt], bf_[ct], acc[rt][ct]);
      }
  }

  float s = 1.0f;
  if (sa >= 0) s *= fmaxf(u2f(slots[sa]) / 127.0f, 1e-8f);
  if (sb >= 0) s *= fmaxf(u2f(slots[sb]) / 127.0f, 1e-8f);
  #pragma unroll
  for (int rt = 0; rt < 4; ++rt)
    #pragma unroll
    for (int r = 0; r < 4; ++r) {
      int row = bm + wr * 64 + rt * 16 + 4 * g + r;
      #pragma unroll
      for (int ct = 0; ct < 4; ++ct) {
        int col = bn + wc * 64 + ct * 16 + c15;
        C[(size_t)row * N + col] = acc[rt][ct][r] * s + bias[col];
      }
    }
}

// Flash attention on integer-domain bf16 X. Layout X[n=l*B+b][f]:
// f<1024: q2_int, 1024..2047: k_int, 2048..3071: v_int.
// grid (qb=32, bh=32), 256 thr = 4 waves; wave w owns q rows [w*16, w*16+16).
__global__ __launch_bounds__(256) void attn_mfma_k(const bf16_t* __restrict__ X,
                                                   float* __restrict__ heads,
                                                   const unsigned* __restrict__ slots) {
  int qb = blockIdx.x, bh = blockIdx.y;
  int b = bh >> 4, h = bh & 15;
  int t = threadIdx.x;
  int w = t >> 6, l = t & 63, c15 = l & 15, g = l >> 4;

  float s_x = fmaxf(u2f(slots[2]) / 127.0f, 1e-8f);
  float s_q = fmaxf((u2f(slots[3]) * s_x) * 0.125f / 127.0f, 1e-8f);
  float qkscale = s_q * s_x;

  __shared__ __align__(16) bf16_t Ks[64][72];   // [kcol][d]
  __shared__ __align__(16) bf16_t Vs[64][72];   // [d][kcol] (transposed)
  __shared__ __align__(16) bf16_t Ph[4][16][72];
  __shared__ __align__(16) bf16_t Pl[4][16][72];

  // Q a-frags, held in registers for the whole kernel
  int qrow = qb * 64 + w * 16 + c15;
  const bf16_t* qbase = X + ((size_t)qrow * BATCH + b) * F3 + h * HDIM;
  s16x8 qf0 = *(const s16x8*)(qbase + g * 8);
  s16x8 qf1 = *(const s16x8*)(qbase + 32 + g * 8);

  f32x4 acc_o[4] = {};
  float m_prev[4] = {-INFINITY, -INFINITY, -INFINITY, -INFINITY};
  float lsum[4] = {0.0f, 0.0f, 0.0f, 0.0f};

  for (int kt = 0; kt < L_SEQ / 64; ++kt) {
    __syncthreads();   // prev-iter Ks/Vs reads complete
    #pragma unroll
    for (int i = 0; i < 2; ++i) {
      int s = t + i * 256;
      int row = s >> 3, seg = s & 7;
      size_t tok = (size_t)(kt * 64 + row) * BATCH + b;
      *(uint4*)&Ks[row][seg * 8] = *(const uint4*)&X[tok * F3 + EMB + h * HDIM + seg * 8];
      uint4 vraw = *(const uint4*)&X[tok * F3 + 2 * EMB + h * HDIM + seg * 8];
      bf16_t* vv = (bf16_t*)&vraw;
      #pragma unroll
      for (int j = 0; j < 8; ++j) Vs[seg * 8 + j][row] = vv[j];
    }
    __syncthreads();   // Ks/Vs visible

    // S = q2 @ k^T (exact integer arithmetic in bf16 MFMA)
    f32x4 accs[4] = {};
    #pragma unroll
    for (int ct = 0; ct < 4; ++ct) {
      s16x8 kf0 = *(const s16x8*)&Ks[ct * 16 + c15][g * 8];
      s16x8 kf1 = *(const s16x8*)&Ks[ct * 16 + c15][32 + g * 8];
      accs[ct] = MFMA16(qf0, kf0, accs[ct]);
      accs[ct] = MFMA16(qf1, kf1, accs[ct]);
    }

    // online softmax; lane owns rows 4g+r of this wave's 16-row strip
    float f_[4];
    #pragma unroll
    for (int r = 0; r < 4; ++r) {
      float pm = fmaxf(fmaxf(accs[0][r], accs[1][r]), fmaxf(accs[2][r], accs[3][r])) * qkscale;
      pm = fmaxf(pm, __shfl_xor(pm, 1));
      pm = fmaxf(pm, __shfl_xor(pm, 2));
      pm = fmaxf(pm, __shfl_xor(pm, 4));
      pm = fmaxf(pm, __shfl_xor(pm, 8));
      float mnew = fmaxf(m_prev[r], pm);
      f_[r] = expf(m_prev[r] - mnew);
      int qr = 4 * g + r;
      float ps = 0.0f;
      #pragma unroll
      for (int ct = 0; ct < 4; ++ct) {
        float p = expf(accs[ct][r] * qkscale - mnew);
        ps += p;
        bf16_t hi = (bf16_t)p;
        Ph[w][qr][ct * 16 + c15] = hi;
        Pl[w][qr][ct * 16 + c15] = (bf16_t)(p - (float)hi);
      }
      ps += __shfl_xor(ps, 1);
      ps += __shfl_xor(ps, 2);
      ps += __shfl_xor(ps, 4);
      ps += __shfl_xor(ps, 8);
      lsum[r] = lsum[r] * f_[r] + ps;
      m_prev[r] = mnew;
    }
    // rescale O
    #pragma unroll
    for (int dt = 0; dt < 4; ++dt)
      #pragma unroll
      for (int r = 0; r < 4; ++r) acc_o[dt][r] *= f_[r];

    // PV: O += (P_hi + P_lo) @ V   (per-wave P region; same-wave LDS dep)
    s16x8 ph0 = *(const s16x8*)&Ph[w][c15][g * 8];
    s16x8 ph1 = *(const s16x8*)&Ph[w][c15][32 + g * 8];
    s16x8 pl0 = *(const s16x8*)&Pl[w][c15][g * 8];
    s16x8 pl1 = *(const s16x8*)&Pl[w][c15][32 + g * 8];
    #pragma unroll
    for (int dt = 0; dt < 4; ++dt) {
      s16x8 vf0 = *(const s16x8*)&Vs[dt * 16 + c15][g * 8];
      s16x8 vf1 = *(const s16x8*)&Vs[dt * 16 + c15][32 + g * 8];
      acc_o[dt] = MFMA16(ph0, vf0, acc_o[dt]);
      acc_o[dt] = MFMA16(ph1, vf1, acc_o[dt]);
      acc_o[dt] = MFMA16(pl0, vf0, acc_o[dt]);
      acc_o[dt] = MFMA16(pl1, vf1, acc_o[dt]);
    }
  }

  // heads = O * s_x / l
  #pragma unroll
  for (int dt = 0; dt < 4; ++dt)
    #pragma unroll
    for (int r = 0; r < 4; ++r) {
      int row = qb * 64 + w * 16 + 4 * g + r;
      float o = acc_o[dt][r] * s_x / lsum[r];
      heads[((size_t)row * BATCH + b) * EMB + h * HDIM + dt * 16 + c15] = o;
    }
}

extern "C" void kernel_launch(void* const* d_in, const int* in_sizes, int n_in,
                              void* d_out, int out_size, void* d_ws, size_t ws_size,
                              hipStream_t stream) {
  (void)in_sizes; (void)n_in; (void)out_size; (void)ws_size;
  const float* query = (const float*)d_in[0];
  const float* in_w  = (const float*)d_in[3];
  const float* in_b  = (const float*)d_in[4];
  const float* out_w = (const float*)d_in[5];
  const float* out_b = (const float*)d_in[6];
  float* out = (float*)d_out;

  unsigned* slots = (unsigned*)d_ws;
  char* p = (char*)d_ws + 256;
  bf16_t* q_hi   = (bf16_t*)p;                  p += (size_t)NROWS * EMB * 2;   // 8 MB
  bf16_t* q_lo   = (bf16_t*)p;                  p += (size_t)NROWS * EMB * 2;   // 8 MB
  bf16_t* Wi_int = (bf16_t*)p;                  p += (size_t)F3 * EMB * 2;      // 6 MB
  bf16_t* Wo_int = (bf16_t*)p;                  p += (size_t)EMB * EMB * 2;     // 2 MB
  float*  X_f32  = (float*)p;                   p += (size_t)NROWS * F3 * 4;    // 48 MB
  bf16_t* X_int  = (bf16_t*)p;                                                  // 24 MB
  bf16_t* heads_int = (bf16_t*)X_f32;  // reuse X_f32 region after X quantized
  float*  heads_f32 = out;             // d_out doubles as heads staging

  hipMemsetAsync(d_ws, 0, 256, stream);

  dim3 b256(256);
  // weight fake-quant -> integer bf16
  absmax_k<<<1024, b256, 0, stream>>>(in_w, F3 * EMB / 4, slots + 0);
  absmax_k<<<512,  b256, 0, stream>>>(out_w, EMB * EMB / 4, slots + 1);
  quantf_k<<<1024, b256, 0, stream>>>(in_w, Wi_int, F3 * EMB / 4, slots, 0);
  quantf_k<<<512,  b256, 0, stream>>>(out_w, Wo_int, EMB * EMB / 4, slots, 1);

  // query hi/lo split
  split_k<<<2048, b256, 0, stream>>>(query, q_hi, q_lo, NROWS * EMB / 4);

  // GEMM1: X = (q_hi+q_lo) @ Wi_int^T * s_wi + in_b
  gemm_bt_mfma_k<2><<<dim3(F3 / 128, NROWS / 128), b256, 0, stream>>>(
      q_hi, q_lo, Wi_int, in_b, X_f32, NROWS, F3, EMB, slots, -1, 0);

  // X fake-quant -> integer bf16
  absmax_k<<<2048, b256, 0, stream>>>(X_f32, NROWS * F3 / 4, slots + 2);
  quantf_k<<<2048, b256, 0, stream>>>(X_f32, X_int, NROWS * F3 / 4, slots, 2);

  // q2 = fq(Xq/8) in place on Q-region
  absmax_bf16_qreg_k<<<1024, b256, 0, stream>>>(X_int, slots + 3);
  requant_qreg_k<<<1024, b256, 0, stream>>>(X_int, slots);

  // attention -> heads_f32 (= d_out)
  attn_mfma_k<<<dim3(L_SEQ / 64, BATCH * NH), b256, 0, stream>>>(X_int, heads_f32, slots);

  // heads fake-quant -> integer bf16
  absmax_k<<<1024, b256, 0, stream>>>(heads_f32, NROWS * EMB / 4, slots + 4);
  quantf_k<<<1024, b256, 0, stream>>>(heads_f32, heads_int, NROWS * EMB / 4, slots, 4);

  // GEMM2: y = heads_int @ Wo_int^T * (s_h*s_wo) + out_b  -> d_out
  gemm_bt_mfma_k<1><<<dim3(EMB / 128, NROWS / 128), b256, 0, stream>>>(
      heads_int, nullptr, Wo_int, out_b, out, NROWS, EMB, EMB, slots, 4, 1);

  // final fake-quant in place
  absmax_k<<<1024, b256, 0, stream>>>(out, NROWS * EMB / 4, slots + 5);
  quant_k<<<1024, b256, 0, stream>>>(out, NROWS * EMB / 4, slots, 5);
}

// Round 3
// 306.967 us; speedup vs baseline: 3.7240x; 1.4281x over previous
//
#include <hip/hip_runtime.h>
#include <math.h>

#define L_SEQ 2048
#define BATCH 2
#define EMB 1024
#define NH 16
#define HDIM 64
#define F3 3072
#define NROWS 4096   // L_SEQ * BATCH

typedef __bf16 bf16_t;
typedef short s16x8 __attribute__((ext_vector_type(8)));
typedef float f32x4 __attribute__((ext_vector_type(4)));

#define MFMA16(a, b, c) __builtin_amdgcn_mfma_f32_16x16x32_bf16(a, b, c, 0, 0, 0)

// ws slots (uint bits of fp32 absmax):
// [0]=absmax(in_w) [1]=absmax(out_w) [2]=absmax(X) [3]=max|int| of Xq Q-region
// [4]=absmax(heads) [5]=absmax(y)

__device__ __forceinline__ float u2f(unsigned u) { return __uint_as_float(u); }

__device__ __forceinline__ unsigned short bfb(bf16_t x) {
  union { bf16_t b; unsigned short u; } c; c.b = x; return c.u;
}

__device__ __forceinline__ void blockmax_commit(float m, unsigned* slot) {
  #pragma unroll
  for (int o = 1; o < 64; o <<= 1) m = fmaxf(m, __shfl_xor(m, o));
  __shared__ float sm_[4];
  if ((threadIdx.x & 63) == 0) sm_[threadIdx.x >> 6] = m;
  __syncthreads();
  if (threadIdx.x == 0) {
    float mm = fmaxf(fmaxf(sm_[0], sm_[1]), fmaxf(sm_[2], sm_[3]));
    atomicMax(slot, __float_as_uint(mm));
  }
}

__global__ __launch_bounds__(256) void absmax_k(const float* __restrict__ x, int n4,
                                                unsigned* __restrict__ slot) {
  const float4* x4 = (const float4*)x;
  float m = 0.0f;
  for (int i = blockIdx.x * blockDim.x + threadIdx.x; i < n4; i += gridDim.x * blockDim.x) {
    float4 v = x4[i];
    m = fmaxf(m, fmaxf(fmaxf(fabsf(v.x), fabsf(v.y)), fmaxf(fabsf(v.z), fabsf(v.w))));
  }
  blockmax_commit(m, slot);
}

// fp32 -> integer-valued bf16 (n = rint(clip(x/s, -128, 127)))
__global__ __launch_bounds__(256) void quantf_k(const float* __restrict__ x,
                                                bf16_t* __restrict__ y, int n4,
                                                const unsigned* __restrict__ slots, int sloti) {
  float s = fmaxf(u2f(slots[sloti]) / 127.0f, 1e-8f);
  const float4* x4 = (const float4*)x;
  for (int i = blockIdx.x * blockDim.x + threadIdx.x; i < n4; i += gridDim.x * blockDim.x) {
    float4 v = x4[i];
    bf16_t o[4];
    o[0] = (bf16_t)rintf(fminf(fmaxf(v.x / s, -128.0f), 127.0f));
    o[1] = (bf16_t)rintf(fminf(fmaxf(v.y / s, -128.0f), 127.0f));
    o[2] = (bf16_t)rintf(fminf(fmaxf(v.z / s, -128.0f), 127.0f));
    o[3] = (bf16_t)rintf(fminf(fmaxf(v.w / s, -128.0f), 127.0f));
    *(uint2*)&y[(size_t)i * 4] = *(uint2*)o;
  }
}

// X pass: fp32 -> int bf16, plus fused max|int| over Q-region (cols<1024) -> slots[3]
__global__ __launch_bounds__(256) void quantX_k(const float* __restrict__ x,
                                                bf16_t* __restrict__ y,
                                                unsigned* __restrict__ slots) {
  float s = fmaxf(u2f(slots[2]) / 127.0f, 1e-8f);
  float qm = 0.0f;
  const int n8 = NROWS * F3 / 8;
  for (int i = blockIdx.x * blockDim.x + threadIdx.x; i < n8; i += gridDim.x * blockDim.x) {
    float4 v0 = *(const float4*)&x[(size_t)i * 8];
    float4 v1 = *(const float4*)&x[(size_t)i * 8 + 4];
    float vv[8] = {v0.x, v0.y, v0.z, v0.w, v1.x, v1.y, v1.z, v1.w};
    bf16_t o[8];
    float lm = 0.0f;
    #pragma unroll
    for (int j = 0; j < 8; ++j) {
      float q = rintf(fminf(fmaxf(vv[j] / s, -128.0f), 127.0f));
      o[j] = (bf16_t)q;
      lm = fmaxf(lm, fabsf(q));
    }
    if ((i % 384) < 128) qm = fmaxf(qm, lm);
    *(uint4*)&y[(size_t)i * 8] = *(uint4*)o;
  }
  blockmax_commit(qm, slots + 3);
}

// fp32 real-valued fake-quant in place (final output)
__global__ __launch_bounds__(256) void quant_k(float* __restrict__ x, int n4,
                                               const unsigned* __restrict__ slots, int sloti) {
  float s = fmaxf(u2f(slots[sloti]) / 127.0f, 1e-8f);
  float4* x4 = (float4*)x;
  for (int i = blockIdx.x * blockDim.x + threadIdx.x; i < n4; i += gridDim.x * blockDim.x) {
    float4 v = x4[i];
    v.x = rintf(fminf(fmaxf(v.x / s, -128.0f), 127.0f)) * s;
    v.y = rintf(fminf(fmaxf(v.y / s, -128.0f), 127.0f)) * s;
    v.z = rintf(fminf(fmaxf(v.z / s, -128.0f), 127.0f)) * s;
    v.w = rintf(fminf(fmaxf(v.w / s, -128.0f), 127.0f)) * s;
    x4[i] = v;
  }
}

// fp32 -> (hi, lo) bf16 pair
__global__ __launch_bounds__(256) void split_k(const float* __restrict__ x,
                                               bf16_t* __restrict__ hi,
                                               bf16_t* __restrict__ lo, int n4) {
  const float4* x4 = (const float4*)x;
  for (int i = blockIdx.x * blockDim.x + threadIdx.x; i < n4; i += gridDim.x * blockDim.x) {
    float4 v = x4[i];
    bf16_t h[4], l[4];
    float vv[4] = {v.x, v.y, v.z, v.w};
    #pragma unroll
    for (int j = 0; j < 4; ++j) {
      h[j] = (bf16_t)vv[j];
      l[j] = (bf16_t)(vv[j] - (float)h[j]);
    }
    *(uint2*)&hi[(size_t)i * 4] = *(uint2*)h;
    *(uint2*)&lo[(size_t)i * 4] = *(uint2*)l;
  }
}

// in-place requant of Q-region: n2 = rint(clip(((n*s_x)*0.125)/s_q, -128, 127))
__global__ __launch_bounds__(256) void requant_qreg_k(bf16_t* __restrict__ X,
                                                      const unsigned* __restrict__ slots) {
  float s_x = fmaxf(u2f(slots[2]) / 127.0f, 1e-8f);
  float s_q = fmaxf((u2f(slots[3]) * s_x) * 0.125f / 127.0f, 1e-8f);
  const int total = NROWS * (EMB / 8);
  for (int i = blockIdx.x * blockDim.x + threadIdx.x; i < total; i += gridDim.x * blockDim.x) {
    int n = i >> 7, c = i & 127;
    bf16_t* p = X + (size_t)n * F3 + c * 8;
    bf16_t v[8];
    *(uint4*)v = *(const uint4*)p;
    #pragma unroll
    for (int j = 0; j < 8; ++j) {
      float q = ((float)v[j] * s_x) * 0.125f;
      v[j] = (bf16_t)rintf(fminf(fmaxf(q / s_q, -128.0f), 127.0f));
    }
    *(uint4*)p = *(uint4*)v;
  }
}

// V-region of X_int -> Vt[bh][d][token], swizzled-LDS 64x64 tile transpose
__global__ __launch_bounds__(256) void vtrans_k(const bf16_t* __restrict__ X,
                                                bf16_t* __restrict__ Vt) {
  __shared__ __align__(16) bf16_t tile[64][72];
  int tt = blockIdx.x, bh = blockIdx.y;
  int b = bh >> 4, h = bh & 15;
  int t = threadIdx.x;
  #pragma unroll
  for (int i = 0; i < 2; ++i) {
    int s = t + i * 256;
    int tok = s >> 3, seg = s & 7;
    uint4 v = *(const uint4*)&X[((size_t)(tt * 64 + tok) * BATCH + b) * F3 + 2 * EMB + h * HDIM + seg * 8];
    int segs = seg ^ (tok >> 3);           // XOR-swizzle the 8-elem block index
    *(uint4*)&tile[tok][segs * 8] = v;
  }
  __syncthreads();
  #pragma unroll
  for (int i = 0; i < 2; ++i) {
    int s = t + i * 256;
    int d = s >> 3, tseg = s & 7;
    bf16_t o[8];
    #pragma unroll
    for (int e = 0; e < 8; ++e) {
      int tok = tseg * 8 + e;
      o[e] = tile[tok][(((d >> 3) ^ (tok >> 3)) << 3) | (d & 7)];
    }
    *(uint4*)&Vt[((size_t)bh * HDIM + d) * L_SEQ + tt * 64 + tseg * 8] = *(uint4*)o;
  }
}

// C[M,N] = (sum_p A_p[M,K]) @ B[N,K]^T * scale + bias[N]; bf16 in, f32 out.
// Optional fused output-absmax -> slots[smax].
template <int NPARTS>
__global__ __launch_bounds__(256) void gemm_bt_mfma_k(const bf16_t* __restrict__ A0,
                                                      const bf16_t* __restrict__ A1,
                                                      const bf16_t* __restrict__ Bm,
                                                      const float* __restrict__ bias,
                                                      float* __restrict__ C,
                                                      int M, int N, int K,
                                                      unsigned* __restrict__ slots,
                                                      int sa, int sb, int smax) {
  __shared__ __align__(16) bf16_t As[NPARTS][128][40];
  __shared__ __align__(16) bf16_t Bs[128][40];
  int t = threadIdx.x;
  int w = t >> 6, l = t & 63, c15 = l & 15, g = l >> 4;
  int wr = w >> 1, wc = w & 1;
  int bm = blockIdx.y * 128, bn = blockIdx.x * 128;
  f32x4 acc[4][4] = {};

  for (int k0 = 0; k0 < K; k0 += 32) {
    __syncthreads();
    #pragma unroll
    for (int i = 0; i < 2; ++i) {
      int s = t + i * 256;
      int row = s >> 2, seg = s & 3;
      *(uint4*)&As[0][row][seg * 8] = *(const uint4*)&A0[(size_t)(bm + row) * K + k0 + seg * 8];
      if (NPARTS == 2)
        *(uint4*)&As[1][row][seg * 8] = *(const uint4*)&A1[(size_t)(bm + row) * K + k0 + seg * 8];
      *(uint4*)&Bs[row][seg * 8] = *(const uint4*)&Bm[(size_t)(bn + row) * K + k0 + seg * 8];
    }
    __syncthreads();
    s16x8 af[NPARTS][4], bf_[4];
    #pragma unroll
    for (int rt = 0; rt < 4; ++rt) {
      af[0][rt] = *(const s16x8*)&As[0][wr * 64 + rt * 16 + c15][g * 8];
      if (NPARTS == 2) af[1][rt] = *(const s16x8*)&As[1][wr * 64 + rt * 16 + c15][g * 8];
    }
    #pragma unroll
    for (int ct = 0; ct < 4; ++ct)
      bf_[ct] = *(const s16x8*)&Bs[wc * 64 + ct * 16 + c15][g * 8];
    #pragma unroll
    for (int rt = 0; rt < 4; ++rt)
      #pragma unroll
      for (int ct = 0; ct < 4; ++ct) {
        acc[rt][ct] = MFMA16(af[0][rt], bf_[ct], acc[rt][ct]);
        if (NPARTS == 2) acc[rt][ct] = MFMA16(af[1][rt], bf_[ct], acc[rt][ct]);
      }
  }

  float s = 1.0f;
  if (sa >= 0) s *= fmaxf(u2f(slots[sa]) / 127.0f, 1e-8f);
  if (sb >= 0) s *= fmaxf(u2f(slots[sb]) / 127.0f, 1e-8f);
  float vmax = 0.0f;
  #pragma unroll
  for (int rt = 0; rt < 4; ++rt)
    #pragma unroll
    for (int r = 0; r < 4; ++r) {
      int row = bm + wr * 64 + rt * 16 + 4 * g + r;
      #pragma unroll
      for (int ct = 0; ct < 4; ++ct) {
        int col = bn + wc * 64 + ct * 16 + c15;
        float o = acc[rt][ct][r] * s + bias[col];
        vmax = fmaxf(vmax, fabsf(o));
        C[(size_t)row * N + col] = o;
      }
    }
  if (smax >= 0) blockmax_commit(vmax, slots + smax);
}

// Flash attention. X: [tok*B+b][f] f<1024: q2_int, 1024..2047: k_int (v unused here).
// Vt: [bh][d][token]. grid (qb=32, bh=32), 256 thr = 4 waves; wave w: q rows [w*16, w*16+16).
__global__ __launch_bounds__(256) void attn_mfma_k(const bf16_t* __restrict__ X,
                                                   const bf16_t* __restrict__ Vt,
                                                   float* __restrict__ heads,
                                                   unsigned* __restrict__ slots) {
  int qb = blockIdx.x, bh = blockIdx.y;
  int b = bh >> 4, h = bh & 15;
  int t = threadIdx.x;
  int w = t >> 6, l = t & 63, c15 = l & 15, g = l >> 4;

  float s_x = fmaxf(u2f(slots[2]) / 127.0f, 1e-8f);
  float s_q = fmaxf((u2f(slots[3]) * s_x) * 0.125f / 127.0f, 1e-8f);
  const float LOG2E = 1.4426950408889634f;
  float qsl2 = s_q * s_x * LOG2E;   // raw-score -> log2 domain

  __shared__ __align__(16) bf16_t Ks[64][72];   // [kcol][d]
  __shared__ __align__(16) bf16_t Vs[64][72];   // [d][kcol] (from Vt, no transpose here)
  __shared__ unsigned Pp[4][16][68];            // per-wave packed P: hi | lo<<16

  int qrow = qb * 64 + w * 16 + c15;
  const bf16_t* qbase = X + ((size_t)qrow * BATCH + b) * F3 + h * HDIM;
  s16x8 qf0 = *(const s16x8*)(qbase + g * 8);
  s16x8 qf1 = *(const s16x8*)(qbase + 32 + g * 8);
  const bf16_t* vbase = Vt + (size_t)bh * HDIM * L_SEQ;

  f32x4 acc_o[4] = {};
  float m_prev[4] = {-INFINITY, -INFINITY, -INFINITY, -INFINITY};
  float lsum[4] = {0.0f, 0.0f, 0.0f, 0.0f};

  for (int kt = 0; kt < L_SEQ / 64; ++kt) {
    __syncthreads();   // prev-iter Ks/Vs reads complete
    #pragma unroll
    for (int i = 0; i < 2; ++i) {
      int s = t + i * 256;
      int row = s >> 3, seg = s & 7;
      *(uint4*)&Ks[row][seg * 8] =
          *(const uint4*)&X[((size_t)(kt * 64 + row) * BATCH + b) * F3 + EMB + h * HDIM + seg * 8];
      *(uint4*)&Vs[row][seg * 8] =
          *(const uint4*)&vbase[(size_t)row * L_SEQ + kt * 64 + seg * 8];
    }
    __syncthreads();   // Ks/Vs visible

    // S = q2 @ k^T (exact integer arithmetic in bf16 MFMA)
    f32x4 accs[4] = {};
    __builtin_amdgcn_s_setprio(1);
    #pragma unroll
    for (int ct = 0; ct < 4; ++ct) {
      s16x8 kf0 = *(const s16x8*)&Ks[ct * 16 + c15][g * 8];
      s16x8 kf1 = *(const s16x8*)&Ks[ct * 16 + c15][32 + g * 8];
      accs[ct] = MFMA16(qf0, kf0, accs[ct]);
      accs[ct] = MFMA16(qf1, kf1, accs[ct]);
    }
    __builtin_amdgcn_s_setprio(0);

    // online softmax in exp2 domain; lane owns rows 4g+r of the wave's 16-row strip
    float f_[4];
    #pragma unroll
    for (int r = 0; r < 4; ++r) {
      float pm = fmaxf(fmaxf(accs[0][r], accs[1][r]), fmaxf(accs[2][r], accs[3][r]));
      pm = fmaxf(pm, __shfl_xor(pm, 1));
      pm = fmaxf(pm, __shfl_xor(pm, 2));
      pm = fmaxf(pm, __shfl_xor(pm, 4));
      pm = fmaxf(pm, __shfl_xor(pm, 8));
      float mnew = fmaxf(m_prev[r], pm);
      f_[r] = __builtin_amdgcn_exp2f((m_prev[r] - mnew) * qsl2);
      float mq = mnew * qsl2;
      int qr = 4 * g + r;
      float ps = 0.0f;
      #pragma unroll
      for (int ct = 0; ct < 4; ++ct) {
        float p = __builtin_amdgcn_exp2f(fmaf(accs[ct][r], qsl2, -mq));
        ps += p;
        bf16_t hi = (bf16_t)p;
        bf16_t lo = (bf16_t)(p - (float)hi);
        Pp[w][qr][ct * 16 + c15] = (unsigned)bfb(hi) | ((unsigned)bfb(lo) << 16);
      }
      lsum[r] = lsum[r] * f_[r] + ps;   // cross-lane reduce deferred to epilogue
      m_prev[r] = mnew;
    }
    // rescale O
    #pragma unroll
    for (int dt = 0; dt < 4; ++dt)
      #pragma unroll
      for (int r = 0; r < 4; ++r) acc_o[dt][r] *= f_[r];

    // unpack P frags (same-wave LDS dependency, no barrier needed)
    s16x8 ph[2], pl[2];
    #pragma unroll
    for (int f = 0; f < 2; ++f) {
      unsigned pw[8];
      *(uint4*)&pw[0] = *(const uint4*)&Pp[w][c15][f * 32 + g * 8];
      *(uint4*)&pw[4] = *(const uint4*)&Pp[w][c15][f * 32 + g * 8 + 4];
      #pragma unroll
      for (int e = 0; e < 8; ++e) {
        ph[f][e] = (short)(pw[e] & 0xffffu);
        pl[f][e] = (short)(pw[e] >> 16);
      }
    }
    __builtin_amdgcn_s_setprio(1);
    #pragma unroll
    for (int dt = 0; dt < 4; ++dt) {
      s16x8 vf0 = *(const s16x8*)&Vs[dt * 16 + c15][g * 8];
      s16x8 vf1 = *(const s16x8*)&Vs[dt * 16 + c15][32 + g * 8];
      acc_o[dt] = MFMA16(ph[0], vf0, acc_o[dt]);
      acc_o[dt] = MFMA16(ph[1], vf1, acc_o[dt]);
      acc_o[dt] = MFMA16(pl[0], vf0, acc_o[dt]);
      acc_o[dt] = MFMA16(pl[1], vf1, acc_o[dt]);
    }
    __builtin_amdgcn_s_setprio(0);
  }

  // finalize lsum across the 16 lanes sharing each row
  #pragma unroll
  for (int r = 0; r < 4; ++r) {
    float l2 = lsum[r];
    l2 += __shfl_xor(l2, 1);
    l2 += __shfl_xor(l2, 2);
    l2 += __shfl_xor(l2, 4);
    l2 += __shfl_xor(l2, 8);
    lsum[r] = l2;
  }

  // heads = O * s_x / l ; fused absmax -> slots[4]
  float hm = 0.0f;
  #pragma unroll
  for (int dt = 0; dt < 4; ++dt)
    #pragma unroll
    for (int r = 0; r < 4; ++r) {
      int row = qb * 64 + w * 16 + 4 * g + r;
      float o = acc_o[dt][r] * s_x / lsum[r];
      hm = fmaxf(hm, fabsf(o));
      heads[((size_t)row * BATCH + b) * EMB + h * HDIM + dt * 16 + c15] = o;
    }
  blockmax_commit(hm, slots + 4);
}

extern "C" void kernel_launch(void* const* d_in, const int* in_sizes, int n_in,
                              void* d_out, int out_size, void* d_ws, size_t ws_size,
                              hipStream_t stream) {
  (void)in_sizes; (void)n_in; (void)out_size; (void)ws_size;
  const float* query = (const float*)d_in[0];
  const float* in_w  = (const float*)d_in[3];
  const float* in_b  = (const float*)d_in[4];
  const float* out_w = (const float*)d_in[5];
  const float* out_b = (const float*)d_in[6];
  float* out = (float*)d_out;

  unsigned* slots = (unsigned*)d_ws;
  char* p = (char*)d_ws + 256;
  bf16_t* q_hi   = (bf16_t*)p;                  p += (size_t)NROWS * EMB * 2;   // 8 MB
  bf16_t* q_lo   = (bf16_t*)p;                  p += (size_t)NROWS * EMB * 2;   // 8 MB
  bf16_t* Wi_int = (bf16_t*)p;                  p += (size_t)F3 * EMB * 2;      // 6 MB
  bf16_t* Wo_int = (bf16_t*)p;                  p += (size_t)EMB * EMB * 2;     // 2 MB
  float*  X_f32  = (float*)p;                   p += (size_t)NROWS * F3 * 4;    // 48 MB
  bf16_t* X_int  = (bf16_t*)p;                                                  // 24 MB
  bf16_t* Vt     = q_hi;               // q_hi dead after GEMM1; reuse as Vt (8 MB)
  bf16_t* heads_int = (bf16_t*)X_f32;  // X_f32 dead after quantX
  float*  heads_f32 = out;             // d_out doubles as heads staging

  hipMemsetAsync(d_ws, 0, 256, stream);

  dim3 b256(256);
  // weight fake-quant -> integer bf16
  absmax_k<<<1024, b256, 0, stream>>>(in_w, F3 * EMB / 4, slots + 0);
  absmax_k<<<512,  b256, 0, stream>>>(out_w, EMB * EMB / 4, slots + 1);
  quantf_k<<<1024, b256, 0, stream>>>(in_w, Wi_int, F3 * EMB / 4, slots, 0);
  quantf_k<<<512,  b256, 0, stream>>>(out_w, Wo_int, EMB * EMB / 4, slots, 1);

  // query hi/lo split
  split_k<<<2048, b256, 0, stream>>>(query, q_hi, q_lo, NROWS * EMB / 4);

  // GEMM1: X = (q_hi+q_lo) @ Wi_int^T * s_wi + in_b ; fused absmax(X) -> slot2
  gemm_bt_mfma_k<2><<<dim3(F3 / 128, NROWS / 128), b256, 0, stream>>>(
      q_hi, q_lo, Wi_int, in_b, X_f32, NROWS, F3, EMB, slots, -1, 0, 2);

  // X -> int bf16, fused Q-region |int| max -> slot3
  quantX_k<<<2048, b256, 0, stream>>>(X_f32, X_int, slots);

  // q2 = fq(Xq/8) in place on Q-region
  requant_qreg_k<<<1024, b256, 0, stream>>>(X_int, slots);

  // V pre-transpose (into dead q_hi region)
  vtrans_k<<<dim3(L_SEQ / 64, BATCH * NH), b256, 0, stream>>>(X_int, Vt);

  // attention -> heads_f32 (= d_out), fused absmax(heads) -> slot4
  attn_mfma_k<<<dim3(L_SEQ / 64, BATCH * NH), b256, 0, stream>>>(X_int, Vt, heads_f32, slots);

  // heads -> int bf16
  quantf_k<<<1024, b256, 0, stream>>>(heads_f32, heads_int, NROWS * EMB / 4, slots, 4);

  // GEMM2: y = heads_int @ Wo_int^T * (s_h*s_wo) + out_b ; fused absmax(y) -> slot5
  gemm_bt_mfma_k<1><<<dim3(EMB / 128, NROWS / 128), b256, 0, stream>>>(
      heads_int, nullptr, Wo_int, out_b, out, NROWS, EMB, EMB, slots, 4, 1, 5);

  // final fake-quant in place
  quant_k<<<1024, b256, 0, stream>>>(out, NROWS * EMB / 4, slots, 5);
}

// Round 4
// 259.286 us; speedup vs baseline: 4.4088x; 1.1839x over previous
//
#include <hip/hip_runtime.h>
#include <math.h>

#define L_SEQ 2048
#define BATCH 2
#define EMB 1024
#define NH 16
#define HDIM 64
#define F3 3072
#define NROWS 4096   // L_SEQ * BATCH

typedef __bf16 bf16_t;
typedef short s16x8 __attribute__((ext_vector_type(8)));
typedef float f32x4 __attribute__((ext_vector_type(4)));

#define MFMA16(a, b, c) __builtin_amdgcn_mfma_f32_16x16x32_bf16(a, b, c, 0, 0, 0)

// ws slots (uint bits of fp32 absmax):
// [0]=absmax(in_w) [1]=absmax(out_w) [2]=absmax(X) [3]=max|int| of Xq Q-region
// [4]=absmax(heads) [5]=absmax(y)

__device__ __forceinline__ float u2f(unsigned u) { return __uint_as_float(u); }

__device__ __forceinline__ unsigned short bfb(bf16_t x) {
  union { bf16_t b; unsigned short u; } c; c.b = x; return c.u;
}

__device__ __forceinline__ void gload16(const bf16_t* g, bf16_t* lds) {
  __builtin_amdgcn_global_load_lds((const __attribute__((address_space(1))) void*)g,
                                   (__attribute__((address_space(3))) void*)lds, 16, 0, 0);
}

__device__ __forceinline__ void blockmax_commit(float m, unsigned* slot) {
  #pragma unroll
  for (int o = 1; o < 64; o <<= 1) m = fmaxf(m, __shfl_xor(m, o));
  __shared__ float sm_[4];
  if ((threadIdx.x & 63) == 0) sm_[threadIdx.x >> 6] = m;
  __syncthreads();
  if (threadIdx.x == 0) {
    float mm = fmaxf(fmaxf(sm_[0], sm_[1]), fmaxf(sm_[2], sm_[3]));
    atomicMax(slot, __float_as_uint(mm));
  }
}

__global__ __launch_bounds__(256) void absmax_k(const float* __restrict__ x, int n4,
                                                unsigned* __restrict__ slot) {
  const float4* x4 = (const float4*)x;
  float m = 0.0f;
  for (int i = blockIdx.x * blockDim.x + threadIdx.x; i < n4; i += gridDim.x * blockDim.x) {
    float4 v = x4[i];
    m = fmaxf(m, fmaxf(fmaxf(fabsf(v.x), fabsf(v.y)), fmaxf(fabsf(v.z), fabsf(v.w))));
  }
  blockmax_commit(m, slot);
}

// fp32 -> integer-valued bf16 (n = rint(clip(x/s, -128, 127)))
__global__ __launch_bounds__(256) void quantf_k(const float* __restrict__ x,
                                                bf16_t* __restrict__ y, int n4,
                                                const unsigned* __restrict__ slots, int sloti) {
  float s = fmaxf(u2f(slots[sloti]) / 127.0f, 1e-8f);
  const float4* x4 = (const float4*)x;
  for (int i = blockIdx.x * blockDim.x + threadIdx.x; i < n4; i += gridDim.x * blockDim.x) {
    float4 v = x4[i];
    bf16_t o[4];
    o[0] = (bf16_t)rintf(fminf(fmaxf(v.x / s, -128.0f), 127.0f));
    o[1] = (bf16_t)rintf(fminf(fmaxf(v.y / s, -128.0f), 127.0f));
    o[2] = (bf16_t)rintf(fminf(fmaxf(v.z / s, -128.0f), 127.0f));
    o[3] = (bf16_t)rintf(fminf(fmaxf(v.w / s, -128.0f), 127.0f));
    *(uint2*)&y[(size_t)i * 4] = *(uint2*)o;
  }
}

// X pass: fp32 -> int bf16, plus fused max|int| over Q-region (cols<1024) -> slots[3]
__global__ __launch_bounds__(256) void quantX_k(const float* __restrict__ x,
                                                bf16_t* __restrict__ y,
                                                unsigned* __restrict__ slots) {
  float s = fmaxf(u2f(slots[2]) / 127.0f, 1e-8f);
  float qm = 0.0f;
  const int n8 = NROWS * F3 / 8;
  for (int i = blockIdx.x * blockDim.x + threadIdx.x; i < n8; i += gridDim.x * blockDim.x) {
    float4 v0 = *(const float4*)&x[(size_t)i * 8];
    float4 v1 = *(const float4*)&x[(size_t)i * 8 + 4];
    float vv[8] = {v0.x, v0.y, v0.z, v0.w, v1.x, v1.y, v1.z, v1.w};
    bf16_t o[8];
    float lm = 0.0f;
    #pragma unroll
    for (int j = 0; j < 8; ++j) {
      float q = rintf(fminf(fmaxf(vv[j] / s, -128.0f), 127.0f));
      o[j] = (bf16_t)q;
      lm = fmaxf(lm, fabsf(q));
    }
    if ((i % 384) < 128) qm = fmaxf(qm, lm);
    *(uint4*)&y[(size_t)i * 8] = *(uint4*)o;
  }
  blockmax_commit(qm, slots + 3);
}

// fp32 real-valued fake-quant in place (final output)
__global__ __launch_bounds__(256) void quant_k(float* __restrict__ x, int n4,
                                               const unsigned* __restrict__ slots, int sloti) {
  float s = fmaxf(u2f(slots[sloti]) / 127.0f, 1e-8f);
  float4* x4 = (float4*)x;
  for (int i = blockIdx.x * blockDim.x + threadIdx.x; i < n4; i += gridDim.x * blockDim.x) {
    float4 v = x4[i];
    v.x = rintf(fminf(fmaxf(v.x / s, -128.0f), 127.0f)) * s;
    v.y = rintf(fminf(fmaxf(v.y / s, -128.0f), 127.0f)) * s;
    v.z = rintf(fminf(fmaxf(v.z / s, -128.0f), 127.0f)) * s;
    v.w = rintf(fminf(fmaxf(v.w / s, -128.0f), 127.0f)) * s;
    x4[i] = v;
  }
}

// fp32 -> (hi, lo) bf16 pair
__global__ __launch_bounds__(256) void split_k(const float* __restrict__ x,
                                               bf16_t* __restrict__ hi,
                                               bf16_t* __restrict__ lo, int n4) {
  const float4* x4 = (const float4*)x;
  for (int i = blockIdx.x * blockDim.x + threadIdx.x; i < n4; i += gridDim.x * blockDim.x) {
    float4 v = x4[i];
    bf16_t h[4], l[4];
    float vv[4] = {v.x, v.y, v.z, v.w};
    #pragma unroll
    for (int j = 0; j < 4; ++j) {
      h[j] = (bf16_t)vv[j];
      l[j] = (bf16_t)(vv[j] - (float)h[j]);
    }
    *(uint2*)&hi[(size_t)i * 4] = *(uint2*)h;
    *(uint2*)&lo[(size_t)i * 4] = *(uint2*)l;
  }
}

// V-region of X_int -> Vt[bh][d][token], swizzled-LDS 64x64 tile transpose
__global__ __launch_bounds__(256) void vtrans_k(const bf16_t* __restrict__ X,
                                                bf16_t* __restrict__ Vt) {
  __shared__ __align__(16) bf16_t tile[64][72];
  int tt = blockIdx.x, bh = blockIdx.y;
  int b = bh >> 4, h = bh & 15;
  int t = threadIdx.x;
  #pragma unroll
  for (int i = 0; i < 2; ++i) {
    int s = t + i * 256;
    int tok = s >> 3, seg = s & 7;
    uint4 v = *(const uint4*)&X[((size_t)(tt * 64 + tok) * BATCH + b) * F3 + 2 * EMB + h * HDIM + seg * 8];
    int segs = seg ^ (tok >> 3);           // XOR-swizzle the 8-elem block index
    *(uint4*)&tile[tok][segs * 8] = v;
  }
  __syncthreads();
  #pragma unroll
  for (int i = 0; i < 2; ++i) {
    int s = t + i * 256;
    int d = s >> 3, tseg = s & 7;
    bf16_t o[8];
    #pragma unroll
    for (int e = 0; e < 8; ++e) {
      int tok = tseg * 8 + e;
      o[e] = tile[tok][(((d >> 3) ^ (tok >> 3)) << 3) | (d & 7)];
    }
    *(uint4*)&Vt[((size_t)bh * HDIM + d) * L_SEQ + tt * 64 + tseg * 8] = *(uint4*)o;
  }
}

// C[M,N] = (sum_p A_p[M,K]) @ B[N,K]^T * scale + bias[N]; bf16 in, f32 out.
// global_load_lds staging + 2-phase double buffer. Optional fused absmax -> slots[smax].
template <int NPARTS>
__global__ __launch_bounds__(256) void gemm_bt_mfma_k(const bf16_t* __restrict__ A0,
                                                      const bf16_t* __restrict__ A1,
                                                      const bf16_t* __restrict__ Bm,
                                                      const float* __restrict__ bias,
                                                      float* __restrict__ C,
                                                      int M, int N, int K,
                                                      unsigned* __restrict__ slots,
                                                      int sa, int sb, int smax) {
  __shared__ __align__(16) bf16_t sbuf[2][NPARTS + 1][128][32];
  int t = threadIdx.x;
  int w = t >> 6, l = t & 63, c15 = l & 15, g = l >> 4;
  int wr = w >> 1, wc = w & 1;
  int bm = blockIdx.y * 128, bn = blockIdx.x * 128;
  f32x4 acc[4][4] = {};

  auto stage = [&](int bf, int k0) {
    #pragma unroll
    for (int i = 0; i < 2; ++i) {
      int c = i * 256 + t;              // 16B-chunk id 0..511
      int row = c >> 2, sg = c & 3;
      int wb = (i * 256 + w * 64) * 8;  // wave-uniform LDS base (bf16 elems)
      gload16(&A0[(size_t)(bm + row) * K + k0 + sg * 8], &sbuf[bf][0][0][0] + wb);
      if (NPARTS == 2)
        gload16(&A1[(size_t)(bm + row) * K + k0 + sg * 8], &sbuf[bf][1][0][0] + wb);
      gload16(&Bm[(size_t)(bn + row) * K + k0 + sg * 8], &sbuf[bf][NPARTS][0][0] + wb);
    }
  };

  stage(0, 0);
  __syncthreads();
  const int nk = K / 32;
  for (int kt = 0; kt < nk; ++kt) {
    int cur = kt & 1;
    if (kt + 1 < nk) stage(cur ^ 1, (kt + 1) * 32);
    s16x8 af[NPARTS][4], bf_[4];
    #pragma unroll
    for (int rt = 0; rt < 4; ++rt) {
      af[0][rt] = *(const s16x8*)&sbuf[cur][0][wr * 64 + rt * 16 + c15][g * 8];
      if (NPARTS == 2) af[1][rt] = *(const s16x8*)&sbuf[cur][1][wr * 64 + rt * 16 + c15][g * 8];
    }
    #pragma unroll
    for (int ct = 0; ct < 4; ++ct)
      bf_[ct] = *(const s16x8*)&sbuf[cur][NPARTS][wc * 64 + ct * 16 + c15][g * 8];
    __builtin_amdgcn_s_setprio(1);
    #pragma unroll
    for (int rt = 0; rt < 4; ++rt)
      #pragma unroll
      for (int ct = 0; ct < 4; ++ct) {
        acc[rt][ct] = MFMA16(af[0][rt], bf_[ct], acc[rt][ct]);
        if (NPARTS == 2) acc[rt][ct] = MFMA16(af[1][rt], bf_[ct], acc[rt][ct]);
      }
    __builtin_amdgcn_s_setprio(0);
    __syncthreads();
  }

  float s = 1.0f;
  if (sa >= 0) s *= fmaxf(u2f(slots[sa]) / 127.0f, 1e-8f);
  if (sb >= 0) s *= fmaxf(u2f(slots[sb]) / 127.0f, 1e-8f);
  float vmax = 0.0f;
  #pragma unroll
  for (int rt = 0; rt < 4; ++rt)
    #pragma unroll
    for (int r = 0; r < 4; ++r) {
      int row = bm + wr * 64 + rt * 16 + 4 * g + r;
      #pragma unroll
      for (int ct = 0; ct < 4; ++ct) {
        int col = bn + wc * 64 + ct * 16 + c15;
        float o = acc[rt][ct][r] * s + bias[col];
        vmax = fmaxf(vmax, fabsf(o));
        C[(size_t)row * N + col] = o;
      }
    }
  if (smax >= 0) blockmax_commit(vmax, slots + smax);
}

// Flash attention, swapped-operand MFMA (P/O^T lane-local softmax stats).
// X: [tok*B+b][f] f<1024: X_int Q-region (requant fused here), 1024..2047: k_int.
// Vt: [bh][d][token]. grid (qb=32, bh=32), 256 thr = 4 waves; wave w: q rows [w*16, w*16+16).
__global__ __launch_bounds__(256) void attn_mfma_k(const bf16_t* __restrict__ X,
                                                   const bf16_t* __restrict__ Vt,
                                                   float* __restrict__ heads,
                                                   unsigned* __restrict__ slots) {
  int qb = blockIdx.x, bh = blockIdx.y;
  int b = bh >> 4, h = bh & 15;
  int t = threadIdx.x;
  int w = t >> 6, l = t & 63, c15 = l & 15, g = l >> 4;

  float s_x = fmaxf(u2f(slots[2]) / 127.0f, 1e-8f);
  float s_q = fmaxf((u2f(slots[3]) * s_x) * 0.125f / 127.0f, 1e-8f);
  const float LOG2E = 1.4426950408889634f;
  float qsl2 = s_q * s_x * LOG2E;   // raw int-score -> log2 domain

  __shared__ __align__(16) union SmKV {
    struct { bf16_t Ks[64][72]; bf16_t Vs[64][72]; } kv;   // 18432 B
    float Ot[4][16][69];                                   // 17664 B (epilogue overlay)
  } sm;
  __shared__ __align__(16) bf16_t Pl[4][16][136];  // per-wave P: hi cols 0..63, lo 64..127

  // Q frags with fused requant: q2 = rint(clip(((n*s_x)*0.125)/s_q, -128, 127))
  int qrow = qb * 64 + w * 16 + c15;
  const bf16_t* qbase = X + ((size_t)qrow * BATCH + b) * F3 + h * HDIM;
  s16x8 qf0, qf1;
  {
    bf16_t qt[8];
    #pragma unroll
    for (int half = 0; half < 2; ++half) {
      *(uint4*)qt = *(const uint4*)(qbase + half * 32 + g * 8);
      #pragma unroll
      for (int j = 0; j < 8; ++j) {
        float q = ((float)qt[j] * s_x) * 0.125f;
        qt[j] = (bf16_t)rintf(fminf(fmaxf(q / s_q, -128.0f), 127.0f));
      }
      if (half == 0) qf0 = *(s16x8*)qt; else qf1 = *(s16x8*)qt;
    }
  }

  // staging geometry: chunk s = t + i*256 -> row s>>3 (0..63), seg s&7
  int r0 = t >> 3, sg0 = t & 7;
  const size_t tokstride = (size_t)BATCH * F3;
  const bf16_t* kp = X + (size_t)r0 * tokstride + (size_t)b * F3 + EMB + h * HDIM + sg0 * 8;
  const bf16_t* vbase = Vt + (size_t)bh * HDIM * L_SEQ;
  const bf16_t* vp = vbase + (size_t)r0 * L_SEQ + sg0 * 8;

  uint4 gk0, gk1, gv0, gv1;
  auto loadg = [&](int kt) {
    size_t ko = (size_t)kt * 64 * tokstride;
    gk0 = *(const uint4*)(kp + ko);
    gk1 = *(const uint4*)(kp + ko + 32 * tokstride);
    int vo = kt * 64;
    gv0 = *(const uint4*)(vp + vo);
    gv1 = *(const uint4*)(vp + vo + 32 * L_SEQ);
  };
  auto write_lds = [&]() {
    *(uint4*)&sm.kv.Ks[r0][sg0 * 8] = gk0;
    *(uint4*)&sm.kv.Ks[r0 + 32][sg0 * 8] = gk1;
    *(uint4*)&sm.kv.Vs[r0][sg0 * 8] = gv0;
    *(uint4*)&sm.kv.Vs[r0 + 32][sg0 * 8] = gv1;
  };

  f32x4 acc_o[4] = {};
  float m_prev = -INFINITY, lsum = 0.0f;

  loadg(0);
  write_lds();
  __syncthreads();

  const int NT = L_SEQ / 64;
  for (int kt = 0; kt < NT; ++kt) {
    // 1. QK^T swapped: A=K (rows=tokens), B=Q (rows=q) -> S[k_local][q=c15]
    f32x4 accs[4] = {};
    __builtin_amdgcn_s_setprio(1);
    #pragma unroll
    for (int ct = 0; ct < 4; ++ct) {
      s16x8 kf0 = *(const s16x8*)&sm.kv.Ks[ct * 16 + c15][g * 8];
      s16x8 kf1 = *(const s16x8*)&sm.kv.Ks[ct * 16 + c15][32 + g * 8];
      accs[ct] = MFMA16(kf0, qf0, accs[ct]);
      accs[ct] = MFMA16(kf1, qf1, accs[ct]);
    }
    __builtin_amdgcn_s_setprio(0);

    // 2. issue next-tile global loads (latency hides under softmax+PV)
    if (kt + 1 < NT) loadg(kt + 1);

    // 3. in-register softmax for row q=c15 (lane holds 16 of 64 scores)
    float pm = accs[0][0];
    #pragma unroll
    for (int ct = 0; ct < 4; ++ct)
      #pragma unroll
      for (int r = 0; r < 4; ++r) pm = fmaxf(pm, accs[ct][r]);
    pm = fmaxf(pm, __shfl_xor(pm, 16));
    pm = fmaxf(pm, __shfl_xor(pm, 32));
    float mnew = fmaxf(m_prev, pm);
    float f_ = __builtin_amdgcn_exp2f((m_prev - mnew) * qsl2);
    float mq = mnew * qsl2;
    float ps = 0.0f;
    #pragma unroll
    for (int ct = 0; ct < 4; ++ct) {
      float p[4];
      #pragma unroll
      for (int r = 0; r < 4; ++r) p[r] = __builtin_amdgcn_exp2f(fmaf(accs[ct][r], qsl2, -mq));
      ps += (p[0] + p[1]) + (p[2] + p[3]);
      bf16_t h_[4], l_[4];
      #pragma unroll
      for (int r = 0; r < 4; ++r) { h_[r] = (bf16_t)p[r]; l_[r] = (bf16_t)(p[r] - (float)h_[r]); }
      uint2 hiw, low;
      hiw.x = (unsigned)bfb(h_[0]) | ((unsigned)bfb(h_[1]) << 16);
      hiw.y = (unsigned)bfb(h_[2]) | ((unsigned)bfb(h_[3]) << 16);
      low.x = (unsigned)bfb(l_[0]) | ((unsigned)bfb(l_[1]) << 16);
      low.y = (unsigned)bfb(l_[2]) | ((unsigned)bfb(l_[3]) << 16);
      *(uint2*)&Pl[w][c15][ct * 16 + g * 4] = hiw;
      *(uint2*)&Pl[w][c15][64 + ct * 16 + g * 4] = low;
    }
    lsum = lsum * f_ + ps;
    m_prev = mnew;

    // 4. rescale O^T (factor lane-local in q=c15); skip when uniformly 1
    if (!__all(f_ == 1.0f)) {
      #pragma unroll
      for (int dt = 0; dt < 4; ++dt)
        #pragma unroll
        for (int r = 0; r < 4; ++r) acc_o[dt][r] *= f_;
    }

    // 5. P frags (same-wave LDS RAW, in-order DS pipe) + PV swapped: A=V^T, B=P
    s16x8 pf_h0 = *(const s16x8*)&Pl[w][c15][g * 8];
    s16x8 pf_h1 = *(const s16x8*)&Pl[w][c15][32 + g * 8];
    s16x8 pf_l0 = *(const s16x8*)&Pl[w][c15][64 + g * 8];
    s16x8 pf_l1 = *(const s16x8*)&Pl[w][c15][96 + g * 8];
    __builtin_amdgcn_s_setprio(1);
    #pragma unroll
    for (int dt = 0; dt < 4; ++dt) {
      s16x8 vf0 = *(const s16x8*)&sm.kv.Vs[dt * 16 + c15][g * 8];
      s16x8 vf1 = *(const s16x8*)&sm.kv.Vs[dt * 16 + c15][32 + g * 8];
      acc_o[dt] = MFMA16(vf0, pf_h0, acc_o[dt]);
      acc_o[dt] = MFMA16(vf1, pf_h1, acc_o[dt]);
      acc_o[dt] = MFMA16(vf0, pf_l0, acc_o[dt]);
      acc_o[dt] = MFMA16(vf1, pf_l1, acc_o[dt]);
    }
    __builtin_amdgcn_s_setprio(0);

    // 6. rotate staging: all waves done reading, then write next tile
    __syncthreads();
    if (kt + 1 < NT) write_lds();
    __syncthreads();
  }

  // lsum finalize over the 4 lanes sharing q=c15
  lsum += __shfl_xor(lsum, 16);
  lsum += __shfl_xor(lsum, 32);
  float inv = s_x / lsum;

  // O^T -> Ot[w][q][d] (conflict-free stride 69), fused absmax
  float hm = 0.0f;
  #pragma unroll
  for (int dt = 0; dt < 4; ++dt)
    #pragma unroll
    for (int r = 0; r < 4; ++r) {
      float o = acc_o[dt][r] * inv;
      hm = fmaxf(hm, fabsf(o));
      sm.Ot[w][c15][dt * 16 + 4 * g + r] = o;
    }
  // coalesced read-back + global store (same-wave dependency only)
  int ql = l >> 2, cs = l & 3;
  #pragma unroll
  for (int j = 0; j < 4; ++j) {
    int cch = cs + 4 * j;
    float4 v = *(const float4*)&sm.Ot[w][ql][cch * 4];
    int row = qb * 64 + w * 16 + ql;
    *(float4*)&heads[((size_t)row * BATCH + b) * EMB + h * HDIM + cch * 4] = v;
  }
  blockmax_commit(hm, slots + 4);
}

extern "C" void kernel_launch(void* const* d_in, const int* in_sizes, int n_in,
                              void* d_out, int out_size, void* d_ws, size_t ws_size,
                              hipStream_t stream) {
  (void)in_sizes; (void)n_in; (void)out_size; (void)ws_size;
  const float* query = (const float*)d_in[0];
  const float* in_w  = (const float*)d_in[3];
  const float* in_b  = (const float*)d_in[4];
  const float* out_w = (const float*)d_in[5];
  const float* out_b = (const float*)d_in[6];
  float* out = (float*)d_out;

  unsigned* slots = (unsigned*)d_ws;
  char* p = (char*)d_ws + 256;
  bf16_t* q_hi   = (bf16_t*)p;                  p += (size_t)NROWS * EMB * 2;   // 8 MB
  bf16_t* q_lo   = (bf16_t*)p;                  p += (size_t)NROWS * EMB * 2;   // 8 MB
  bf16_t* Wi_int = (bf16_t*)p;                  p += (size_t)F3 * EMB * 2;      // 6 MB
  bf16_t* Wo_int = (bf16_t*)p;                  p += (size_t)EMB * EMB * 2;     // 2 MB
  float*  X_f32  = (float*)p;                   p += (size_t)NROWS * F3 * 4;    // 48 MB
  bf16_t* X_int  = (bf16_t*)p;                                                  // 24 MB
  bf16_t* Vt     = q_hi;               // q_hi dead after GEMM1; reuse as Vt (8 MB)
  bf16_t* heads_int = (bf16_t*)X_f32;  // X_f32 dead after quantX
  float*  heads_f32 = out;             // d_out doubles as heads staging

  hipMemsetAsync(d_ws, 0, 256, stream);

  dim3 b256(256);
  // weight fake-quant -> integer bf16
  absmax_k<<<1024, b256, 0, stream>>>(in_w, F3 * EMB / 4, slots + 0);
  absmax_k<<<512,  b256, 0, stream>>>(out_w, EMB * EMB / 4, slots + 1);
  quantf_k<<<1024, b256, 0, stream>>>(in_w, Wi_int, F3 * EMB / 4, slots, 0);
  quantf_k<<<512,  b256, 0, stream>>>(out_w, Wo_int, EMB * EMB / 4, slots, 1);

  // query hi/lo split
  split_k<<<2048, b256, 0, stream>>>(query, q_hi, q_lo, NROWS * EMB / 4);

  // GEMM1: X = (q_hi+q_lo) @ Wi_int^T * s_wi + in_b ; fused absmax(X) -> slot2
  gemm_bt_mfma_k<2><<<dim3(F3 / 128, NROWS / 128), b256, 0, stream>>>(
      q_hi, q_lo, Wi_int, in_b, X_f32, NROWS, F3, EMB, slots, -1, 0, 2);

  // X -> int bf16, fused Q-region |int| max -> slot3
  quantX_k<<<2048, b256, 0, stream>>>(X_f32, X_int, slots);

  // V pre-transpose (into dead q_hi region)
  vtrans_k<<<dim3(L_SEQ / 64, BATCH * NH), b256, 0, stream>>>(X_int, Vt);

  // attention (q requant fused) -> heads_f32 (= d_out), fused absmax(heads) -> slot4
  attn_mfma_k<<<dim3(L_SEQ / 64, BATCH * NH), b256, 0, stream>>>(X_int, Vt, heads_f32, slots);

  // heads -> int bf16
  quantf_k<<<1024, b256, 0, stream>>>(heads_f32, heads_int, NROWS * EMB / 4, slots, 4);

  // GEMM2: y = heads_int @ Wo_int^T * (s_h*s_wo) + out_b ; fused absmax(y) -> slot5
  gemm_bt_mfma_k<1><<<dim3(EMB / 128, NROWS / 128), b256, 0, stream>>>(
      heads_int, nullptr, Wo_int, out_b, out, NROWS, EMB, EMB, slots, 4, 1, 5);

  // final fake-quant in place
  quant_k<<<1024, b256, 0, stream>>>(out, NROWS * EMB / 4, slots, 5);
}

// Round 6
// 257.326 us; speedup vs baseline: 4.4424x; 1.0076x over previous
//
#include <hip/hip_runtime.h>
#include <math.h>

#define L_SEQ 2048
#define BATCH 2
#define EMB 1024
#define NH 16
#define HDIM 64
#define F3 3072
#define NROWS 4096   // L_SEQ * BATCH

typedef __bf16 bf16_t;
typedef short s16x8 __attribute__((ext_vector_type(8)));
typedef float f32x4 __attribute__((ext_vector_type(4)));

#define MFMA16(a, b, c) __builtin_amdgcn_mfma_f32_16x16x32_bf16(a, b, c, 0, 0, 0)

// ws slots (uint bits of fp32 absmax):
// [0]=absmax(in_w) [1]=absmax(out_w) [2]=absmax(X) [3]=max|int| of Xq Q-region
// [4]=absmax(heads) [5]=absmax(y)

__device__ __forceinline__ float u2f(unsigned u) { return __uint_as_float(u); }

__device__ __forceinline__ unsigned short bfb(bf16_t x) {
  union { bf16_t b; unsigned short u; } c; c.b = x; return c.u;
}

__device__ __forceinline__ void gload16(const bf16_t* g, bf16_t* lds) {
  __builtin_amdgcn_global_load_lds((const __attribute__((address_space(1))) void*)g,
                                   (__attribute__((address_space(3))) void*)lds, 16, 0, 0);
}

__device__ __forceinline__ void blockmax_commit(float m, unsigned* slot) {
  #pragma unroll
  for (int o = 1; o < 64; o <<= 1) m = fmaxf(m, __shfl_xor(m, o));
  __shared__ float sm_[4];
  if ((threadIdx.x & 63) == 0) sm_[threadIdx.x >> 6] = m;
  __syncthreads();
  if (threadIdx.x == 0) {
    float mm = fmaxf(fmaxf(sm_[0], sm_[1]), fmaxf(sm_[2], sm_[3]));
    atomicMax(slot, __float_as_uint(mm));
  }
}

// absmax of in_w -> slot0 and out_w -> slot1, one launch
__global__ __launch_bounds__(256) void wabsmax_k(const float* __restrict__ wi,
                                                 const float* __restrict__ wo,
                                                 unsigned* __restrict__ slots) {
  float m0 = 0.0f, m1 = 0.0f;
  const int n0 = F3 * EMB / 4, n1 = EMB * EMB / 4;
  for (int i = blockIdx.x * blockDim.x + threadIdx.x; i < n0; i += gridDim.x * blockDim.x) {
    float4 v = ((const float4*)wi)[i];
    m0 = fmaxf(m0, fmaxf(fmaxf(fabsf(v.x), fabsf(v.y)), fmaxf(fabsf(v.z), fabsf(v.w))));
  }
  for (int i = blockIdx.x * blockDim.x + threadIdx.x; i < n1; i += gridDim.x * blockDim.x) {
    float4 v = ((const float4*)wo)[i];
    m1 = fmaxf(m1, fmaxf(fmaxf(fabsf(v.x), fabsf(v.y)), fmaxf(fabsf(v.z), fabsf(v.w))));
  }
  blockmax_commit(m0, slots + 0);
  blockmax_commit(m1, slots + 1);
}

// fused prep: quant(in_w)->Wi_int, quant(out_w)->Wo_int, split(query)->q_hi/q_lo
__global__ __launch_bounds__(256) void prep_k(const float* __restrict__ wi,
                                              const float* __restrict__ wo,
                                              const float* __restrict__ query,
                                              bf16_t* __restrict__ Wi_int,
                                              bf16_t* __restrict__ Wo_int,
                                              bf16_t* __restrict__ q_hi,
                                              bf16_t* __restrict__ q_lo,
                                              const unsigned* __restrict__ slots) {
  float s0 = fmaxf(u2f(slots[0]) / 127.0f, 1e-8f);
  float s1 = fmaxf(u2f(slots[1]) / 127.0f, 1e-8f);
  const int n0 = F3 * EMB / 4, n1 = EMB * EMB / 4, n2 = NROWS * EMB / 4;
  for (int i = blockIdx.x * blockDim.x + threadIdx.x; i < n0; i += gridDim.x * blockDim.x) {
    float4 v = ((const float4*)wi)[i];
    bf16_t o[4];
    o[0] = (bf16_t)rintf(fminf(fmaxf(v.x / s0, -128.0f), 127.0f));
    o[1] = (bf16_t)rintf(fminf(fmaxf(v.y / s0, -128.0f), 127.0f));
    o[2] = (bf16_t)rintf(fminf(fmaxf(v.z / s0, -128.0f), 127.0f));
    o[3] = (bf16_t)rintf(fminf(fmaxf(v.w / s0, -128.0f), 127.0f));
    *(uint2*)&Wi_int[(size_t)i * 4] = *(uint2*)o;
  }
  for (int i = blockIdx.x * blockDim.x + threadIdx.x; i < n1; i += gridDim.x * blockDim.x) {
    float4 v = ((const float4*)wo)[i];
    bf16_t o[4];
    o[0] = (bf16_t)rintf(fminf(fmaxf(v.x / s1, -128.0f), 127.0f));
    o[1] = (bf16_t)rintf(fminf(fmaxf(v.y / s1, -128.0f), 127.0f));
    o[2] = (bf16_t)rintf(fminf(fmaxf(v.z / s1, -128.0f), 127.0f));
    o[3] = (bf16_t)rintf(fminf(fmaxf(v.w / s1, -128.0f), 127.0f));
    *(uint2*)&Wo_int[(size_t)i * 4] = *(uint2*)o;
  }
  for (int i = blockIdx.x * blockDim.x + threadIdx.x; i < n2; i += gridDim.x * blockDim.x) {
    float4 v = ((const float4*)query)[i];
    bf16_t h[4], l[4];
    float vv[4] = {v.x, v.y, v.z, v.w};
    #pragma unroll
    for (int j = 0; j < 4; ++j) {
      h[j] = (bf16_t)vv[j];
      l[j] = (bf16_t)(vv[j] - (float)h[j]);
    }
    *(uint2*)&q_hi[(size_t)i * 4] = *(uint2*)h;
    *(uint2*)&q_lo[(size_t)i * 4] = *(uint2*)l;
  }
}

// X pass over Q+K cols (0..2047): fp32 -> int bf16, fused Q-region |int| max -> slots[3]
__global__ __launch_bounds__(256) void quantX_k(const float* __restrict__ x,
                                                bf16_t* __restrict__ y,
                                                unsigned* __restrict__ slots) {
  float s = fmaxf(u2f(slots[2]) / 127.0f, 1e-8f);
  float qm = 0.0f;
  const int n8 = NROWS * 256;   // 2048 cols / 8 per row
  for (int i = blockIdx.x * blockDim.x + threadIdx.x; i < n8; i += gridDim.x * blockDim.x) {
    int row = i >> 8, ch = i & 255;
    const float* px = x + (size_t)row * F3 + ch * 8;
    float4 v0 = *(const float4*)px;
    float4 v1 = *(const float4*)(px + 4);
    float vv[8] = {v0.x, v0.y, v0.z, v0.w, v1.x, v1.y, v1.z, v1.w};
    bf16_t o[8];
    float lm = 0.0f;
    #pragma unroll
    for (int j = 0; j < 8; ++j) {
      float q = rintf(fminf(fmaxf(vv[j] / s, -128.0f), 127.0f));
      o[j] = (bf16_t)q;
      lm = fmaxf(lm, fabsf(q));
    }
    if (ch < 128) qm = fmaxf(qm, lm);
    *(uint4*)&y[(size_t)row * F3 + ch * 8] = *(uint4*)o;
  }
  blockmax_commit(qm, slots + 3);
}

// fp32 real-valued fake-quant in place (final output)
__global__ __launch_bounds__(256) void quant_k(float* __restrict__ x, int n4,
                                               const unsigned* __restrict__ slots, int sloti) {
  float s = fmaxf(u2f(slots[sloti]) / 127.0f, 1e-8f);
  float4* x4 = (float4*)x;
  for (int i = blockIdx.x * blockDim.x + threadIdx.x; i < n4; i += gridDim.x * blockDim.x) {
    float4 v = x4[i];
    v.x = rintf(fminf(fmaxf(v.x / s, -128.0f), 127.0f)) * s;
    v.y = rintf(fminf(fmaxf(v.y / s, -128.0f), 127.0f)) * s;
    v.z = rintf(fminf(fmaxf(v.z / s, -128.0f), 127.0f)) * s;
    v.w = rintf(fminf(fmaxf(v.w / s, -128.0f), 127.0f)) * s;
    x4[i] = v;
  }
}

// fp32 -> integer-valued bf16 (heads)
__global__ __launch_bounds__(256) void quantf_k(const float* __restrict__ x,
                                                bf16_t* __restrict__ y, int n4,
                                                const unsigned* __restrict__ slots, int sloti) {
  float s = fmaxf(u2f(slots[sloti]) / 127.0f, 1e-8f);
  const float4* x4 = (const float4*)x;
  for (int i = blockIdx.x * blockDim.x + threadIdx.x; i < n4; i += gridDim.x * blockDim.x) {
    float4 v = x4[i];
    bf16_t o[4];
    o[0] = (bf16_t)rintf(fminf(fmaxf(v.x / s, -128.0f), 127.0f));
    o[1] = (bf16_t)rintf(fminf(fmaxf(v.y / s, -128.0f), 127.0f));
    o[2] = (bf16_t)rintf(fminf(fmaxf(v.z / s, -128.0f), 127.0f));
    o[3] = (bf16_t)rintf(fminf(fmaxf(v.w / s, -128.0f), 127.0f));
    *(uint2*)&y[(size_t)i * 4] = *(uint2*)o;
  }
}

// V region of X_f32 -> quant -> Vt[bh][d][token] (swizzled-LDS 64x64 transpose)
__global__ __launch_bounds__(256) void vtrans_k(const float* __restrict__ X,
                                                bf16_t* __restrict__ Vt,
                                                const unsigned* __restrict__ slots) {
  float s = fmaxf(u2f(slots[2]) / 127.0f, 1e-8f);
  __shared__ __align__(16) bf16_t tile[64][72];
  int tt = blockIdx.x, bh = blockIdx.y;
  int b = bh >> 4, h = bh & 15;
  int t = threadIdx.x;
  #pragma unroll
  for (int i = 0; i < 2; ++i) {
    int s_ = t + i * 256;
    int tok = s_ >> 3, seg = s_ & 7;
    const float* px = X + ((size_t)(tt * 64 + tok) * BATCH + b) * F3 + 2 * EMB + h * HDIM + seg * 8;
    float4 v0 = *(const float4*)px;
    float4 v1 = *(const float4*)(px + 4);
    float vv[8] = {v0.x, v0.y, v0.z, v0.w, v1.x, v1.y, v1.z, v1.w};
    bf16_t o[8];
    #pragma unroll
    for (int j = 0; j < 8; ++j)
      o[j] = (bf16_t)rintf(fminf(fmaxf(vv[j] / s, -128.0f), 127.0f));
    int segs = seg ^ (tok >> 3);
    *(uint4*)&tile[tok][segs * 8] = *(uint4*)o;
  }
  __syncthreads();
  #pragma unroll
  for (int i = 0; i < 2; ++i) {
    int s_ = t + i * 256;
    int d = s_ >> 3, tseg = s_ & 7;
    bf16_t o[8];
    #pragma unroll
    for (int e = 0; e < 8; ++e) {
      int tok = tseg * 8 + e;
      o[e] = tile[tok][(((d >> 3) ^ (tok >> 3)) << 3) | (d & 7)];
    }
    *(uint4*)&Vt[((size_t)bh * HDIM + d) * L_SEQ + tt * 64 + tseg * 8] = *(uint4*)o;
  }
}

// C[M,N] = (sum_p A_p[M,K]) @ B[N,K]^T * scale + bias[N]; bf16 in, f32 out.
// global_load_lds + 2-phase dbuf + XCD-swizzled block ids. Fused absmax -> slots[smax].
template <int NPARTS>
__global__ __launch_bounds__(256) void gemm_bt_mfma_k(const bf16_t* __restrict__ A0,
                                                      const bf16_t* __restrict__ A1,
                                                      const bf16_t* __restrict__ Bm,
                                                      const float* __restrict__ bias,
                                                      float* __restrict__ C,
                                                      int M, int N, int K,
                                                      unsigned* __restrict__ slots,
                                                      int sa, int sb, int smax) {
  __shared__ __align__(16) bf16_t sbuf[2][NPARTS + 1][128][32];
  int t = threadIdx.x;
  int w = t >> 6, l = t & 63, c15 = l & 15, g = l >> 4;
  int wr = w >> 1, wc = w & 1;
  // bijective XCD swizzle (nwg % 8 == 0 for both GEMMs)
  int nx = gridDim.x;
  int fid = blockIdx.y * nx + blockIdx.x;
  int qq = (nx * gridDim.y) >> 3;
  int swz = (fid & 7) * qq + (fid >> 3);
  int bm = (swz / nx) * 128, bn = (swz % nx) * 128;
  f32x4 acc[4][4] = {};

  auto stage = [&](int bf, int k0) {
    #pragma unroll
    for (int i = 0; i < 2; ++i) {
      int c = i * 256 + t;              // 16B-chunk id 0..511
      int row = c >> 2, sg = c & 3;
      int wb = (i * 256 + w * 64) * 8;  // wave-uniform LDS base (bf16 elems)
      gload16(&A0[(size_t)(bm + row) * K + k0 + sg * 8], &sbuf[bf][0][0][0] + wb);
      if (NPARTS == 2)
        gload16(&A1[(size_t)(bm + row) * K + k0 + sg * 8], &sbuf[bf][1][0][0] + wb);
      gload16(&Bm[(size_t)(bn + row) * K + k0 + sg * 8], &sbuf[bf][NPARTS][0][0] + wb);
    }
  };

  stage(0, 0);
  __syncthreads();
  const int nk = K / 32;
  for (int kt = 0; kt < nk; ++kt) {
    int cur = kt & 1;
    if (kt + 1 < nk) stage(cur ^ 1, (kt + 1) * 32);
    s16x8 af[NPARTS][4], bf_[4];
    #pragma unroll
    for (int rt = 0; rt < 4; ++rt) {
      af[0][rt] = *(const s16x8*)&sbuf[cur][0][wr * 64 + rt * 16 + c15][g * 8];
      if (NPARTS == 2) af[1][rt] = *(const s16x8*)&sbuf[cur][1][wr * 64 + rt * 16 + c15][g * 8];
    }
    #pragma unroll
    for (int ct = 0; ct < 4; ++ct)
      bf_[ct] = *(const s16x8*)&sbuf[cur][NPARTS][wc * 64 + ct * 16 + c15][g * 8];
    __builtin_amdgcn_s_setprio(1);
    #pragma unroll
    for (int rt = 0; rt < 4; ++rt)
      #pragma unroll
      for (int ct = 0; ct < 4; ++ct) {
        acc[rt][ct] = MFMA16(af[0][rt], bf_[ct], acc[rt][ct]);
        if (NPARTS == 2) acc[rt][ct] = MFMA16(af[1][rt], bf_[ct], acc[rt][ct]);
      }
    __builtin_amdgcn_s_setprio(0);
    __syncthreads();
  }

  float s = 1.0f;
  if (sa >= 0) s *= fmaxf(u2f(slots[sa]) / 127.0f, 1e-8f);
  if (sb >= 0) s *= fmaxf(u2f(slots[sb]) / 127.0f, 1e-8f);
  float vmax = 0.0f;
  #pragma unroll
  for (int rt = 0; rt < 4; ++rt)
    #pragma unroll
    for (int r = 0; r < 4; ++r) {
      int row = bm + wr * 64 + rt * 16 + 4 * g + r;
      #pragma unroll
      for (int ct = 0; ct < 4; ++ct) {
        int col = bn + wc * 64 + ct * 16 + c15;
        float o = acc[rt][ct][r] * s + bias[col];
        vmax = fmaxf(vmax, fabsf(o));
        C[(size_t)row * N + col] = o;
      }
    }
  if (smax >= 0) blockmax_commit(vmax, slots + smax);
}

// Flash attention, swapped-operand MFMA (round-4 numerics: cast-based P hi/lo, no defer).
__global__ __launch_bounds__(256) void attn_mfma_k(const bf16_t* __restrict__ X,
                                                   const bf16_t* __restrict__ Vt,
                                                   float* __restrict__ heads,
                                                   unsigned* __restrict__ slots) {
  int qb = blockIdx.x, bh = blockIdx.y;
  int b = bh >> 4, h = bh & 15;
  int t = threadIdx.x;
  int w = t >> 6, l = t & 63, c15 = l & 15, g = l >> 4;

  float s_x = fmaxf(u2f(slots[2]) / 127.0f, 1e-8f);
  float s_q = fmaxf((u2f(slots[3]) * s_x) * 0.125f / 127.0f, 1e-8f);
  const float LOG2E = 1.4426950408889634f;
  float qsl2 = s_q * s_x * LOG2E;   // raw int-score -> log2 domain

  __shared__ __align__(16) union SmKV {
    struct { bf16_t Ks[64][72]; bf16_t Vs[64][72]; } kv;   // 18432 B
    float Ot[4][16][69];                                   // epilogue overlay
  } sm;
  __shared__ __align__(16) bf16_t Pl[4][16][136];  // per-wave P: hi cols 0..63, lo 64..127

  // Q frags with fused requant: q2 = rint(clip(((n*s_x)*0.125)/s_q, -128, 127))
  int qrow = qb * 64 + w * 16 + c15;
  const bf16_t* qbase = X + ((size_t)qrow * BATCH + b) * F3 + h * HDIM;
  s16x8 qf0, qf1;
  {
    bf16_t qt[8];
    #pragma unroll
    for (int half = 0; half < 2; ++half) {
      *(uint4*)qt = *(const uint4*)(qbase + half * 32 + g * 8);
      #pragma unroll
      for (int j = 0; j < 8; ++j) {
        float q = ((float)qt[j] * s_x) * 0.125f;
        qt[j] = (bf16_t)rintf(fminf(fmaxf(q / s_q, -128.0f), 127.0f));
      }
      if (half == 0) qf0 = *(s16x8*)qt; else qf1 = *(s16x8*)qt;
    }
  }

  int r0 = t >> 3, sg0 = t & 7;
  const size_t tokstride = (size_t)BATCH * F3;
  const bf16_t* kp = X + (size_t)r0 * tokstride + (size_t)b * F3 + EMB + h * HDIM + sg0 * 8;
  const bf16_t* vbase = Vt + (size_t)bh * HDIM * L_SEQ;
  const bf16_t* vp = vbase + (size_t)r0 * L_SEQ + sg0 * 8;

  uint4 gk0, gk1, gv0, gv1;
  auto loadg = [&](int kt) {
    size_t ko = (size_t)kt * 64 * tokstride;
    gk0 = *(const uint4*)(kp + ko);
    gk1 = *(const uint4*)(kp + ko + 32 * tokstride);
    int vo = kt * 64;
    gv0 = *(const uint4*)(vp + vo);
    gv1 = *(const uint4*)(vp + vo + 32 * L_SEQ);
  };
  auto write_lds = [&]() {
    *(uint4*)&sm.kv.Ks[r0][sg0 * 8] = gk0;
    *(uint4*)&sm.kv.Ks[r0 + 32][sg0 * 8] = gk1;
    *(uint4*)&sm.kv.Vs[r0][sg0 * 8] = gv0;
    *(uint4*)&sm.kv.Vs[r0 + 32][sg0 * 8] = gv1;
  };

  f32x4 acc_o[4] = {};
  float m_prev = -INFINITY, lsum = 0.0f;

  loadg(0);
  write_lds();
  __syncthreads();

  const int NT = L_SEQ / 64;
  for (int kt = 0; kt < NT; ++kt) {
    // issue next-tile global loads first (latency hides under QK+softmax+PV)
    if (kt + 1 < NT) loadg(kt + 1);

    // QK^T swapped: A=K (rows=tokens), B=Q (cols=q=c15)
    f32x4 accs[4] = {};
    __builtin_amdgcn_s_setprio(1);
    #pragma unroll
    for (int ct = 0; ct < 4; ++ct) {
      s16x8 kf0 = *(const s16x8*)&sm.kv.Ks[ct * 16 + c15][g * 8];
      s16x8 kf1 = *(const s16x8*)&sm.kv.Ks[ct * 16 + c15][32 + g * 8];
      accs[ct] = MFMA16(kf0, qf0, accs[ct]);
      accs[ct] = MFMA16(kf1, qf1, accs[ct]);
    }
    __builtin_amdgcn_s_setprio(0);

    // in-register softmax for q=c15 (lane holds 16 of 64 scores)
    float pm = accs[0][0];
    #pragma unroll
    for (int ct = 0; ct < 4; ++ct)
      #pragma unroll
      for (int r = 0; r < 4; ++r) pm = fmaxf(pm, accs[ct][r]);
    pm = fmaxf(pm, __shfl_xor(pm, 16));
    pm = fmaxf(pm, __shfl_xor(pm, 32));
    float mnew = fmaxf(m_prev, pm);
    float f_ = __builtin_amdgcn_exp2f((m_prev - mnew) * qsl2);
    float mq = mnew * qsl2;
    float ps = 0.0f;
    #pragma unroll
    for (int ct = 0; ct < 4; ++ct) {
      float p[4];
      #pragma unroll
      for (int r = 0; r < 4; ++r) p[r] = __builtin_amdgcn_exp2f(fmaf(accs[ct][r], qsl2, -mq));
      ps += (p[0] + p[1]) + (p[2] + p[3]);
      bf16_t h_[4], l_[4];
      #pragma unroll
      for (int r = 0; r < 4; ++r) { h_[r] = (bf16_t)p[r]; l_[r] = (bf16_t)(p[r] - (float)h_[r]); }
      uint2 hw, lw;
      hw.x = (unsigned)bfb(h_[0]) | ((unsigned)bfb(h_[1]) << 16);
      hw.y = (unsigned)bfb(h_[2]) | ((unsigned)bfb(h_[3]) << 16);
      lw.x = (unsigned)bfb(l_[0]) | ((unsigned)bfb(l_[1]) << 16);
      lw.y = (unsigned)bfb(l_[2]) | ((unsigned)bfb(l_[3]) << 16);
      *(uint2*)&Pl[w][c15][ct * 16 + g * 4] = hw;
      *(uint2*)&Pl[w][c15][64 + ct * 16 + g * 4] = lw;
    }
    lsum = lsum * f_ + ps;
    m_prev = mnew;

    // rescale O^T (factor lane-local in q=c15); skip when uniformly 1
    if (!__all(f_ == 1.0f)) {
      #pragma unroll
      for (int dt = 0; dt < 4; ++dt)
        #pragma unroll
        for (int r = 0; r < 4; ++r) acc_o[dt][r] *= f_;
    }

    // P frags (same-wave LDS RAW) + PV swapped: A=V^T, B=P
    s16x8 pf_h0 = *(const s16x8*)&Pl[w][c15][g * 8];
    s16x8 pf_h1 = *(const s16x8*)&Pl[w][c15][32 + g * 8];
    s16x8 pf_l0 = *(const s16x8*)&Pl[w][c15][64 + g * 8];
    s16x8 pf_l1 = *(const s16x8*)&Pl[w][c15][96 + g * 8];
    __builtin_amdgcn_s_setprio(1);
    #pragma unroll
    for (int dt = 0; dt < 4; ++dt) {
      s16x8 vf0 = *(const s16x8*)&sm.kv.Vs[dt * 16 + c15][g * 8];
      s16x8 vf1 = *(const s16x8*)&sm.kv.Vs[dt * 16 + c15][32 + g * 8];
      acc_o[dt] = MFMA16(vf0, pf_h0, acc_o[dt]);
      acc_o[dt] = MFMA16(vf1, pf_h1, acc_o[dt]);
      acc_o[dt] = MFMA16(vf0, pf_l0, acc_o[dt]);
      acc_o[dt] = MFMA16(vf1, pf_l1, acc_o[dt]);
    }
    __builtin_amdgcn_s_setprio(0);

    __syncthreads();
    if (kt + 1 < NT) write_lds();
    __syncthreads();
  }

  lsum += __shfl_xor(lsum, 16);
  lsum += __shfl_xor(lsum, 32);
  float inv = s_x / lsum;

  float hm = 0.0f;
  #pragma unroll
  for (int dt = 0; dt < 4; ++dt)
    #pragma unroll
    for (int r = 0; r < 4; ++r) {
      float o = acc_o[dt][r] * inv;
      hm = fmaxf(hm, fabsf(o));
      sm.Ot[w][c15][dt * 16 + 4 * g + r] = o;
    }
  int ql = l >> 2, cs = l & 3;
  #pragma unroll
  for (int j = 0; j < 4; ++j) {
    int cch = cs + 4 * j;
    float4 v = *(const float4*)&sm.Ot[w][ql][cch * 4];
    int row = qb * 64 + w * 16 + ql;
    *(float4*)&heads[((size_t)row * BATCH + b) * EMB + h * HDIM + cch * 4] = v;
  }
  blockmax_commit(hm, slots + 4);
}

extern "C" void kernel_launch(void* const* d_in, const int* in_sizes, int n_in,
                              void* d_out, int out_size, void* d_ws, size_t ws_size,
                              hipStream_t stream) {
  (void)in_sizes; (void)n_in; (void)out_size; (void)ws_size;
  const float* query = (const float*)d_in[0];
  const float* in_w  = (const float*)d_in[3];
  const float* in_b  = (const float*)d_in[4];
  const float* out_w = (const float*)d_in[5];
  const float* out_b = (const float*)d_in[6];
  float* out = (float*)d_out;

  unsigned* slots = (unsigned*)d_ws;
  char* p = (char*)d_ws + 256;
  bf16_t* q_hi   = (bf16_t*)p;                  p += (size_t)NROWS * EMB * 2;   // 8 MB
  bf16_t* q_lo   = (bf16_t*)p;                  p += (size_t)NROWS * EMB * 2;   // 8 MB
  bf16_t* Wi_int = (bf16_t*)p;                  p += (size_t)F3 * EMB * 2;      // 6 MB
  bf16_t* Wo_int = (bf16_t*)p;                  p += (size_t)EMB * EMB * 2;     // 2 MB
  float*  X_f32  = (float*)p;                   p += (size_t)NROWS * F3 * 4;    // 48 MB
  bf16_t* X_int  = (bf16_t*)p;                                                  // 24 MB
  bf16_t* Vt     = q_hi;               // q_hi dead after GEMM1; reuse (8 MB)
  bf16_t* heads_int = (bf16_t*)X_f32;  // X_f32 dead after quantX+vtrans
  float*  heads_f32 = out;             // d_out doubles as heads staging

  hipMemsetAsync(d_ws, 0, 256, stream);

  dim3 b256(256);
  // weight absmax (one launch), then fused quant-weights + query split
  wabsmax_k<<<768, b256, 0, stream>>>(in_w, out_w, slots);
  prep_k<<<1024, b256, 0, stream>>>(in_w, out_w, query, Wi_int, Wo_int, q_hi, q_lo, slots);

  // GEMM1: X = (q_hi+q_lo) @ Wi_int^T * s_wi + in_b ; fused absmax(X) -> slot2
  gemm_bt_mfma_k<2><<<dim3(F3 / 128, NROWS / 128), b256, 0, stream>>>(
      q_hi, q_lo, Wi_int, in_b, X_f32, NROWS, F3, EMB, slots, -1, 0, 2);

  // X Q/K cols -> int bf16, fused Q-region |int| max -> slot3
  quantX_k<<<2048, b256, 0, stream>>>(X_f32, X_int, slots);

  // V region: quant + transpose from X_f32 (into dead q_hi region)
  vtrans_k<<<dim3(L_SEQ / 64, BATCH * NH), b256, 0, stream>>>(X_f32, Vt, slots);

  // attention (q requant fused) -> heads_f32 (= d_out), fused absmax(heads) -> slot4
  attn_mfma_k<<<dim3(L_SEQ / 64, BATCH * NH), b256, 0, stream>>>(X_int, Vt, heads_f32, slots);

  // heads -> int bf16
  quantf_k<<<1024, b256, 0, stream>>>(heads_f32, heads_int, NROWS * EMB / 4, slots, 4);

  // GEMM2: y = heads_int @ Wo_int^T * (s_h*s_wo) + out_b ; fused absmax(y) -> slot5
  gemm_bt_mfma_k<1><<<dim3(EMB / 128, NROWS / 128), b256, 0, stream>>>(
      heads_int, nullptr, Wo_int, out_b, out, NROWS, EMB, EMB, slots, 4, 1, 5);

  // final fake-quant in place
  quant_k<<<1024, b256, 0, stream>>>(out, NROWS * EMB / 4, slots, 5);
}

// Round 7
// 247.698 us; speedup vs baseline: 4.6151x; 1.0389x over previous
//
#include <hip/hip_runtime.h>
#include <math.h>

#define L_SEQ 2048
#define BATCH 2
#define EMB 1024
#define NH 16
#define HDIM 64
#define F3 3072
#define NROWS 4096   // L_SEQ * BATCH

typedef __bf16 bf16_t;
typedef short s16x8 __attribute__((ext_vector_type(8)));
typedef float f32x4 __attribute__((ext_vector_type(4)));

#define MFMA16(a, b, c) __builtin_amdgcn_mfma_f32_16x16x32_bf16(a, b, c, 0, 0, 0)

// ws slots (uint bits of fp32 absmax):
// [0]=absmax(in_w) [1]=absmax(out_w) [2]=absmax(X) [3]=max|int| of Xq Q-region
// [4]=absmax(heads) [5]=absmax(y)

__device__ __forceinline__ float u2f(unsigned u) { return __uint_as_float(u); }

__device__ __forceinline__ void gload16(const bf16_t* g, bf16_t* lds) {
  __builtin_amdgcn_global_load_lds((const __attribute__((address_space(1))) void*)g,
                                   (__attribute__((address_space(3))) void*)lds, 16, 0, 0);
}

__device__ __forceinline__ void blockmax_commit(float m, unsigned* slot) {
  #pragma unroll
  for (int o = 1; o < 64; o <<= 1) m = fmaxf(m, __shfl_xor(m, o));
  __shared__ float sm_[4];
  if ((threadIdx.x & 63) == 0) sm_[threadIdx.x >> 6] = m;
  __syncthreads();
  if (threadIdx.x == 0) {
    float mm = fmaxf(fmaxf(sm_[0], sm_[1]), fmaxf(sm_[2], sm_[3]));
    atomicMax(slot, __float_as_uint(mm));
  }
}

// absmax of in_w -> slot0 and out_w -> slot1, one launch
__global__ __launch_bounds__(256) void wabsmax_k(const float* __restrict__ wi,
                                                 const float* __restrict__ wo,
                                                 unsigned* __restrict__ slots) {
  float m0 = 0.0f, m1 = 0.0f;
  const int n0 = F3 * EMB / 4, n1 = EMB * EMB / 4;
  for (int i = blockIdx.x * blockDim.x + threadIdx.x; i < n0; i += gridDim.x * blockDim.x) {
    float4 v = ((const float4*)wi)[i];
    m0 = fmaxf(m0, fmaxf(fmaxf(fabsf(v.x), fabsf(v.y)), fmaxf(fabsf(v.z), fabsf(v.w))));
  }
  for (int i = blockIdx.x * blockDim.x + threadIdx.x; i < n1; i += gridDim.x * blockDim.x) {
    float4 v = ((const float4*)wo)[i];
    m1 = fmaxf(m1, fmaxf(fmaxf(fabsf(v.x), fabsf(v.y)), fmaxf(fabsf(v.z), fabsf(v.w))));
  }
  blockmax_commit(m0, slots + 0);
  blockmax_commit(m1, slots + 1);
}

// fused prep: quant(in_w)->Wi_int, quant(out_w)->Wo_int, split(query)->q_hi/q_lo
__global__ __launch_bounds__(256) void prep_k(const float* __restrict__ wi,
                                              const float* __restrict__ wo,
                                              const float* __restrict__ query,
                                              bf16_t* __restrict__ Wi_int,
                                              bf16_t* __restrict__ Wo_int,
                                              bf16_t* __restrict__ q_hi,
                                              bf16_t* __restrict__ q_lo,
                                              const unsigned* __restrict__ slots) {
  float s0 = fmaxf(u2f(slots[0]) / 127.0f, 1e-8f);
  float s1 = fmaxf(u2f(slots[1]) / 127.0f, 1e-8f);
  const int n0 = F3 * EMB / 4, n1 = EMB * EMB / 4, n2 = NROWS * EMB / 4;
  for (int i = blockIdx.x * blockDim.x + threadIdx.x; i < n0; i += gridDim.x * blockDim.x) {
    float4 v = ((const float4*)wi)[i];
    bf16_t o[4];
    o[0] = (bf16_t)rintf(fminf(fmaxf(v.x / s0, -128.0f), 127.0f));
    o[1] = (bf16_t)rintf(fminf(fmaxf(v.y / s0, -128.0f), 127.0f));
    o[2] = (bf16_t)rintf(fminf(fmaxf(v.z / s0, -128.0f), 127.0f));
    o[3] = (bf16_t)rintf(fminf(fmaxf(v.w / s0, -128.0f), 127.0f));
    *(uint2*)&Wi_int[(size_t)i * 4] = *(uint2*)o;
  }
  for (int i = blockIdx.x * blockDim.x + threadIdx.x; i < n1; i += gridDim.x * blockDim.x) {
    float4 v = ((const float4*)wo)[i];
    bf16_t o[4];
    o[0] = (bf16_t)rintf(fminf(fmaxf(v.x / s1, -128.0f), 127.0f));
    o[1] = (bf16_t)rintf(fminf(fmaxf(v.y / s1, -128.0f), 127.0f));
    o[2] = (bf16_t)rintf(fminf(fmaxf(v.z / s1, -128.0f), 127.0f));
    o[3] = (bf16_t)rintf(fminf(fmaxf(v.w / s1, -128.0f), 127.0f));
    *(uint2*)&Wo_int[(size_t)i * 4] = *(uint2*)o;
  }
  for (int i = blockIdx.x * blockDim.x + threadIdx.x; i < n2; i += gridDim.x * blockDim.x) {
    float4 v = ((const float4*)query)[i];
    bf16_t h[4], l[4];
    float vv[4] = {v.x, v.y, v.z, v.w};
    #pragma unroll
    for (int j = 0; j < 4; ++j) {
      h[j] = (bf16_t)vv[j];
      l[j] = (bf16_t)(vv[j] - (float)h[j]);
    }
    *(uint2*)&q_hi[(size_t)i * 4] = *(uint2*)h;
    *(uint2*)&q_lo[(size_t)i * 4] = *(uint2*)l;
  }
}

// X pass over Q+K cols (0..2047): fp32 -> int bf16, fused Q-region |int| max -> slots[3]
__global__ __launch_bounds__(256) void quantX_k(const float* __restrict__ x,
                                                bf16_t* __restrict__ y,
                                                unsigned* __restrict__ slots) {
  float s = fmaxf(u2f(slots[2]) / 127.0f, 1e-8f);
  float qm = 0.0f;
  const int n8 = NROWS * 256;   // 2048 cols / 8 per row
  for (int i = blockIdx.x * blockDim.x + threadIdx.x; i < n8; i += gridDim.x * blockDim.x) {
    int row = i >> 8, ch = i & 255;
    const float* px = x + (size_t)row * F3 + ch * 8;
    float4 v0 = *(const float4*)px;
    float4 v1 = *(const float4*)(px + 4);
    float vv[8] = {v0.x, v0.y, v0.z, v0.w, v1.x, v1.y, v1.z, v1.w};
    bf16_t o[8];
    float lm = 0.0f;
    #pragma unroll
    for (int j = 0; j < 8; ++j) {
      float q = rintf(fminf(fmaxf(vv[j] / s, -128.0f), 127.0f));
      o[j] = (bf16_t)q;
      lm = fmaxf(lm, fabsf(q));
    }
    if (ch < 128) qm = fmaxf(qm, lm);
    *(uint4*)&y[(size_t)row * F3 + ch * 8] = *(uint4*)o;
  }
  blockmax_commit(qm, slots + 3);
}

// fp32 real-valued fake-quant in place (final output)
__global__ __launch_bounds__(256) void quant_k(float* __restrict__ x, int n4,
                                               const unsigned* __restrict__ slots, int sloti) {
  float s = fmaxf(u2f(slots[sloti]) / 127.0f, 1e-8f);
  float4* x4 = (float4*)x;
  for (int i = blockIdx.x * blockDim.x + threadIdx.x; i < n4; i += gridDim.x * blockDim.x) {
    float4 v = x4[i];
    v.x = rintf(fminf(fmaxf(v.x / s, -128.0f), 127.0f)) * s;
    v.y = rintf(fminf(fmaxf(v.y / s, -128.0f), 127.0f)) * s;
    v.z = rintf(fminf(fmaxf(v.z / s, -128.0f), 127.0f)) * s;
    v.w = rintf(fminf(fmaxf(v.w / s, -128.0f), 127.0f)) * s;
    x4[i] = v;
  }
}

// fp32 -> integer-valued bf16 (heads)
__global__ __launch_bounds__(256) void quantf_k(const float* __restrict__ x,
                                                bf16_t* __restrict__ y, int n4,
                                                const unsigned* __restrict__ slots, int sloti) {
  float s = fmaxf(u2f(slots[sloti]) / 127.0f, 1e-8f);
  const float4* x4 = (const float4*)x;
  for (int i = blockIdx.x * blockDim.x + threadIdx.x; i < n4; i += gridDim.x * blockDim.x) {
    float4 v = x4[i];
    bf16_t o[4];
    o[0] = (bf16_t)rintf(fminf(fmaxf(v.x / s, -128.0f), 127.0f));
    o[1] = (bf16_t)rintf(fminf(fmaxf(v.y / s, -128.0f), 127.0f));
    o[2] = (bf16_t)rintf(fminf(fmaxf(v.z / s, -128.0f), 127.0f));
    o[3] = (bf16_t)rintf(fminf(fmaxf(v.w / s, -128.0f), 127.0f));
    *(uint2*)&y[(size_t)i * 4] = *(uint2*)o;
  }
}

// V region of X_f32 -> quant -> Vt[bh][d][token] (swizzled-LDS 64x64 transpose)
__global__ __launch_bounds__(256) void vtrans_k(const float* __restrict__ X,
                                                bf16_t* __restrict__ Vt,
                                                const unsigned* __restrict__ slots) {
  float s = fmaxf(u2f(slots[2]) / 127.0f, 1e-8f);
  __shared__ __align__(16) bf16_t tile[64][72];
  int tt = blockIdx.x, bh = blockIdx.y;
  int b = bh >> 4, h = bh & 15;
  int t = threadIdx.x;
  #pragma unroll
  for (int i = 0; i < 2; ++i) {
    int s_ = t + i * 256;
    int tok = s_ >> 3, seg = s_ & 7;
    const float* px = X + ((size_t)(tt * 64 + tok) * BATCH + b) * F3 + 2 * EMB + h * HDIM + seg * 8;
    float4 v0 = *(const float4*)px;
    float4 v1 = *(const float4*)(px + 4);
    float vv[8] = {v0.x, v0.y, v0.z, v0.w, v1.x, v1.y, v1.z, v1.w};
    bf16_t o[8];
    #pragma unroll
    for (int j = 0; j < 8; ++j)
      o[j] = (bf16_t)rintf(fminf(fmaxf(vv[j] / s, -128.0f), 127.0f));
    int segs = seg ^ (tok >> 3);
    *(uint4*)&tile[tok][segs * 8] = *(uint4*)o;
  }
  __syncthreads();
  #pragma unroll
  for (int i = 0; i < 2; ++i) {
    int s_ = t + i * 256;
    int d = s_ >> 3, tseg = s_ & 7;
    bf16_t o[8];
    #pragma unroll
    for (int e = 0; e < 8; ++e) {
      int tok = tseg * 8 + e;
      o[e] = tile[tok][(((d >> 3) ^ (tok >> 3)) << 3) | (d & 7)];
    }
    *(uint4*)&Vt[((size_t)bh * HDIM + d) * L_SEQ + tt * 64 + tseg * 8] = *(uint4*)o;
  }
}

// C[M,N] = (sum_p A_p[M,K]) @ B[N,K]^T * scale + bias[N]; bf16 in, f32 out.
// global_load_lds + 2-phase dbuf + XCD-swizzled block ids. Fused absmax -> slots[smax].
template <int NPARTS>
__global__ __launch_bounds__(256) void gemm_bt_mfma_k(const bf16_t* __restrict__ A0,
                                                      const bf16_t* __restrict__ A1,
                                                      const bf16_t* __restrict__ Bm,
                                                      const float* __restrict__ bias,
                                                      float* __restrict__ C,
                                                      int M, int N, int K,
                                                      unsigned* __restrict__ slots,
                                                      int sa, int sb, int smax) {
  __shared__ __align__(16) bf16_t sbuf[2][NPARTS + 1][128][32];
  int t = threadIdx.x;
  int w = t >> 6, l = t & 63, c15 = l & 15, g = l >> 4;
  int wr = w >> 1, wc = w & 1;
  // bijective XCD swizzle (nwg % 8 == 0 for both GEMMs)
  int nx = gridDim.x;
  int fid = blockIdx.y * nx + blockIdx.x;
  int qq = (nx * gridDim.y) >> 3;
  int swz = (fid & 7) * qq + (fid >> 3);
  int bm = (swz / nx) * 128, bn = (swz % nx) * 128;
  f32x4 acc[4][4] = {};

  auto stage = [&](int bf, int k0) {
    #pragma unroll
    for (int i = 0; i < 2; ++i) {
      int c = i * 256 + t;              // 16B-chunk id 0..511
      int row = c >> 2, sg = c & 3;
      int wb = (i * 256 + w * 64) * 8;  // wave-uniform LDS base (bf16 elems)
      gload16(&A0[(size_t)(bm + row) * K + k0 + sg * 8], &sbuf[bf][0][0][0] + wb);
      if (NPARTS == 2)
        gload16(&A1[(size_t)(bm + row) * K + k0 + sg * 8], &sbuf[bf][1][0][0] + wb);
      gload16(&Bm[(size_t)(bn + row) * K + k0 + sg * 8], &sbuf[bf][NPARTS][0][0] + wb);
    }
  };

  stage(0, 0);
  __syncthreads();
  const int nk = K / 32;
  for (int kt = 0; kt < nk; ++kt) {
    int cur = kt & 1;
    if (kt + 1 < nk) stage(cur ^ 1, (kt + 1) * 32);
    s16x8 af[NPARTS][4], bf_[4];
    #pragma unroll
    for (int rt = 0; rt < 4; ++rt) {
      af[0][rt] = *(const s16x8*)&sbuf[cur][0][wr * 64 + rt * 16 + c15][g * 8];
      if (NPARTS == 2) af[1][rt] = *(const s16x8*)&sbuf[cur][1][wr * 64 + rt * 16 + c15][g * 8];
    }
    #pragma unroll
    for (int ct = 0; ct < 4; ++ct)
      bf_[ct] = *(const s16x8*)&sbuf[cur][NPARTS][wc * 64 + ct * 16 + c15][g * 8];
    __builtin_amdgcn_s_setprio(1);
    #pragma unroll
    for (int rt = 0; rt < 4; ++rt)
      #pragma unroll
      for (int ct = 0; ct < 4; ++ct) {
        acc[rt][ct] = MFMA16(af[0][rt], bf_[ct], acc[rt][ct]);
        if (NPARTS == 2) acc[rt][ct] = MFMA16(af[1][rt], bf_[ct], acc[rt][ct]);
      }
    __builtin_amdgcn_s_setprio(0);
    __syncthreads();
  }

  float s = 1.0f;
  if (sa >= 0) s *= fmaxf(u2f(slots[sa]) / 127.0f, 1e-8f);
  if (sb >= 0) s *= fmaxf(u2f(slots[sb]) / 127.0f, 1e-8f);
  float vmax = 0.0f;
  #pragma unroll
  for (int rt = 0; rt < 4; ++rt)
    #pragma unroll
    for (int r = 0; r < 4; ++r) {
      int row = bm + wr * 64 + rt * 16 + 4 * g + r;
      #pragma unroll
      for (int ct = 0; ct < 4; ++ct) {
        int col = bn + wc * 64 + ct * 16 + c15;
        float o = acc[rt][ct][r] * s + bias[col];
        vmax = fmaxf(vmax, fabsf(o));
        C[(size_t)row * N + col] = o;
      }
    }
  if (smax >= 0) blockmax_commit(vmax, slots + smax);
}

// Flash attention, swapped-operand MFMA, tau-permuted K staging (P fully in registers),
// gload_lds double-buffered K/V with XOR-swizzled pre-permuted global source.
// tau: Ks row a holds token kappa(a) = (a&0x20)|((a&0x10)>>2)|((a&0x0C)<<1)|(a&3), so the
// QK output fragment IS the PV B-operand after an in-register repack (no P LDS).
__global__ __launch_bounds__(256) void attn_mfma_k(const bf16_t* __restrict__ X,
                                                   const bf16_t* __restrict__ Vt,
                                                   float* __restrict__ heads,
                                                   unsigned* __restrict__ slots) {
  int qb = blockIdx.x, bh = blockIdx.y;
  int b = bh >> 4, h = bh & 15;
  int t = threadIdx.x;
  int w = t >> 6, l = t & 63, c15 = l & 15, g = l >> 4;

  float s_x = fmaxf(u2f(slots[2]) / 127.0f, 1e-8f);
  float s_q = fmaxf((u2f(slots[3]) * s_x) * 0.125f / 127.0f, 1e-8f);
  const float LOG2E = 1.4426950408889634f;
  float qsl2 = s_q * s_x * LOG2E;   // raw int-score -> log2 domain

  __shared__ __align__(16) union SmKV {
    struct { bf16_t K[2][64][64]; bf16_t V[2][64][64]; } kv;   // 32768 B
    float Ot[4][16][69];                                       // epilogue overlay
  } sm;

  // Q frags with fused requant: q2 = rint(clip(((n*s_x)*0.125)/s_q, -128, 127))
  int qrow = qb * 64 + w * 16 + c15;
  const bf16_t* qbase = X + ((size_t)qrow * BATCH + b) * F3 + h * HDIM;
  s16x8 qf0, qf1;
  {
    bf16_t qt[8];
    #pragma unroll
    for (int half = 0; half < 2; ++half) {
      *(uint4*)qt = *(const uint4*)(qbase + half * 32 + g * 8);
      #pragma unroll
      for (int j = 0; j < 8; ++j) {
        float q = ((float)qt[j] * s_x) * 0.125f;
        qt[j] = (bf16_t)rintf(fminf(fmaxf(q / s_q, -128.0f), 127.0f));
      }
      if (half == 0) qf0 = *(s16x8*)qt; else qf1 = *(s16x8*)qt;
    }
  }

  const size_t tokstride = (size_t)BATCH * F3;
  const bf16_t* kbase = X + (size_t)b * F3 + EMB + h * HDIM;
  const bf16_t* vbase = Vt + (size_t)bh * HDIM * L_SEQ;

  // stage tile kt into buffer buf: linear LDS dest, tau+XOR-swizzle baked into global src
  auto stage = [&](int buf, int kt) {
    #pragma unroll
    for (int i = 0; i < 2; ++i) {
      int c = i * 256 + t;              // chunk 0..511 of K[buf]
      int a = c >> 3, blk = c & 7;
      int kap = (a & 0x20) | ((a & 0x10) >> 2) | ((a & 0x0C) << 1) | (a & 3);
      gload16(kbase + (size_t)(kt * 64 + kap) * tokstride + (blk ^ (a & 7)) * 8,
              &sm.kv.K[buf][0][0] + (i * 256 + w * 64) * 8);
    }
    #pragma unroll
    for (int i = 0; i < 2; ++i) {
      int c = i * 256 + t;              // chunk 0..511 of V[buf]
      int d = c >> 3, blk = c & 7;
      gload16(vbase + (size_t)d * L_SEQ + kt * 64 + (blk ^ (d & 7)) * 8,
              &sm.kv.V[buf][0][0] + (i * 256 + w * 64) * 8);
    }
  };

  f32x4 acc_o[4] = {};
  float m_prev = -INFINITY, lsum = 0.0f;
  int sw = c15 & 7;                     // read swizzle (row&7 == c15&7 for all frag rows)

  stage(0, 0);
  __syncthreads();

  const int NT = L_SEQ / 64;
  int cur = 0;
  for (int kt = 0; kt < NT; ++kt) {
    if (kt + 1 < NT) stage(cur ^ 1, kt + 1);

    // QK^T swapped: A=K (rows = tau-permuted tokens), B=Q (cols=q=c15)
    f32x4 accs[4] = {};
    __builtin_amdgcn_s_setprio(1);
    #pragma unroll
    for (int ct = 0; ct < 4; ++ct) {
      const bf16_t* krow = &sm.kv.K[cur][ct * 16 + c15][0];
      s16x8 kf0 = *(const s16x8*)(krow + (g ^ sw) * 8);
      s16x8 kf1 = *(const s16x8*)(krow + ((g | 4) ^ sw) * 8);
      accs[ct] = MFMA16(kf0, qf0, accs[ct]);
      accs[ct] = MFMA16(kf1, qf1, accs[ct]);
    }
    __builtin_amdgcn_s_setprio(0);

    // in-register softmax for q=c15 (lane holds 16 of 64 scores)
    float pm = accs[0][0];
    #pragma unroll
    for (int ct = 0; ct < 4; ++ct)
      #pragma unroll
      for (int r = 0; r < 4; ++r) pm = fmaxf(pm, accs[ct][r]);
    pm = fmaxf(pm, __shfl_xor(pm, 16));
    pm = fmaxf(pm, __shfl_xor(pm, 32));
    float mnew = fmaxf(m_prev, pm);
    float f_ = __builtin_amdgcn_exp2f((m_prev - mnew) * qsl2);
    float mq = mnew * qsl2;
    float ps = 0.0f;
    bf16_t hh[2][8], ll[2][8];
    #pragma unroll
    for (int ct = 0; ct < 4; ++ct) {
      float p[4];
      #pragma unroll
      for (int r = 0; r < 4; ++r) p[r] = __builtin_amdgcn_exp2f(fmaf(accs[ct][r], qsl2, -mq));
      ps += (p[0] + p[1]) + (p[2] + p[3]);
      #pragma unroll
      for (int r = 0; r < 4; ++r) {
        bf16_t hi = (bf16_t)p[r];
        hh[ct >> 1][(ct & 1) * 4 + r] = hi;
        ll[ct >> 1][(ct & 1) * 4 + r] = (bf16_t)(p[r] - (float)hi);
      }
    }
    lsum = lsum * f_ + ps;
    m_prev = mnew;

    // rescale O^T (factor lane-local in q=c15); skip when uniformly 1
    if (!__all(f_ == 1.0f)) {
      #pragma unroll
      for (int dt = 0; dt < 4; ++dt)
        #pragma unroll
        for (int r = 0; r < 4; ++r) acc_o[dt][r] *= f_;
    }

    // PV swapped: A=V^T, B=P (frags assembled in registers via tau alignment)
    s16x8 pfh0 = *(s16x8*)hh[0], pfh1 = *(s16x8*)hh[1];
    s16x8 pfl0 = *(s16x8*)ll[0], pfl1 = *(s16x8*)ll[1];
    __builtin_amdgcn_s_setprio(1);
    #pragma unroll
    for (int dt = 0; dt < 4; ++dt) {
      const bf16_t* vrow = &sm.kv.V[cur][dt * 16 + c15][0];
      s16x8 vf0 = *(const s16x8*)(vrow + (g ^ sw) * 8);
      s16x8 vf1 = *(const s16x8*)(vrow + ((g | 4) ^ sw) * 8);
      acc_o[dt] = MFMA16(vf0, pfh0, acc_o[dt]);
      acc_o[dt] = MFMA16(vf1, pfh1, acc_o[dt]);
      acc_o[dt] = MFMA16(vf0, pfl0, acc_o[dt]);
      acc_o[dt] = MFMA16(vf1, pfl1, acc_o[dt]);
    }
    __builtin_amdgcn_s_setprio(0);

    __syncthreads();   // drains gload_lds (vmcnt) -> next buffer staged; cur reads done
    cur ^= 1;
  }

  lsum += __shfl_xor(lsum, 16);
  lsum += __shfl_xor(lsum, 32);
  float inv = s_x / lsum;

  // O^T -> Ot[w][q][d] (overlay on K/V union; barrier above guarantees reads done)
  float hm = 0.0f;
  #pragma unroll
  for (int dt = 0; dt < 4; ++dt)
    #pragma unroll
    for (int r = 0; r < 4; ++r) {
      float o = acc_o[dt][r] * inv;
      hm = fmaxf(hm, fabsf(o));
      sm.Ot[w][c15][dt * 16 + 4 * g + r] = o;
    }
  int ql = l >> 2, cs = l & 3;
  #pragma unroll
  for (int j = 0; j < 4; ++j) {
    int cch = cs + 4 * j;
    float4 v = *(const float4*)&sm.Ot[w][ql][cch * 4];
    int row = qb * 64 + w * 16 + ql;
    *(float4*)&heads[((size_t)row * BATCH + b) * EMB + h * HDIM + cch * 4] = v;
  }
  blockmax_commit(hm, slots + 4);
}

extern "C" void kernel_launch(void* const* d_in, const int* in_sizes, int n_in,
                              void* d_out, int out_size, void* d_ws, size_t ws_size,
                              hipStream_t stream) {
  (void)in_sizes; (void)n_in; (void)out_size; (void)ws_size;
  const float* query = (const float*)d_in[0];
  const float* in_w  = (const float*)d_in[3];
  const float* in_b  = (const float*)d_in[4];
  const float* out_w = (const float*)d_in[5];
  const float* out_b = (const float*)d_in[6];
  float* out = (float*)d_out;

  unsigned* slots = (unsigned*)d_ws;
  char* p = (char*)d_ws + 256;
  bf16_t* q_hi   = (bf16_t*)p;                  p += (size_t)NROWS * EMB * 2;   // 8 MB
  bf16_t* q_lo   = (bf16_t*)p;                  p += (size_t)NROWS * EMB * 2;   // 8 MB
  bf16_t* Wi_int = (bf16_t*)p;                  p += (size_t)F3 * EMB * 2;      // 6 MB
  bf16_t* Wo_int = (bf16_t*)p;                  p += (size_t)EMB * EMB * 2;     // 2 MB
  float*  X_f32  = (float*)p;                   p += (size_t)NROWS * F3 * 4;    // 48 MB
  bf16_t* X_int  = (bf16_t*)p;                                                  // 24 MB
  bf16_t* Vt     = q_hi;               // q_hi dead after GEMM1; reuse (8 MB)
  bf16_t* heads_int = (bf16_t*)X_f32;  // X_f32 dead after quantX+vtrans
  float*  heads_f32 = out;             // d_out doubles as heads staging

  hipMemsetAsync(d_ws, 0, 256, stream);

  dim3 b256(256);
  // weight absmax (one launch), then fused quant-weights + query split
  wabsmax_k<<<768, b256, 0, stream>>>(in_w, out_w, slots);
  prep_k<<<1024, b256, 0, stream>>>(in_w, out_w, query, Wi_int, Wo_int, q_hi, q_lo, slots);

  // GEMM1: X = (q_hi+q_lo) @ Wi_int^T * s_wi + in_b ; fused absmax(X) -> slot2
  gemm_bt_mfma_k<2><<<dim3(F3 / 128, NROWS / 128), b256, 0, stream>>>(
      q_hi, q_lo, Wi_int, in_b, X_f32, NROWS, F3, EMB, slots, -1, 0, 2);

  // X Q/K cols -> int bf16, fused Q-region |int| max -> slot3
  quantX_k<<<2048, b256, 0, stream>>>(X_f32, X_int, slots);

  // V region: quant + transpose from X_f32 (into dead q_hi region)
  vtrans_k<<<dim3(L_SEQ / 64, BATCH * NH), b256, 0, stream>>>(X_f32, Vt, slots);

  // attention (q requant fused) -> heads_f32 (= d_out), fused absmax(heads) -> slot4
  attn_mfma_k<<<dim3(L_SEQ / 64, BATCH * NH), b256, 0, stream>>>(X_int, Vt, heads_f32, slots);

  // heads -> int bf16
  quantf_k<<<1024, b256, 0, stream>>>(heads_f32, heads_int, NROWS * EMB / 4, slots, 4);

  // GEMM2: y = heads_int @ Wo_int^T * (s_h*s_wo) + out_b ; fused absmax(y) -> slot5
  gemm_bt_mfma_k<1><<<dim3(EMB / 128, NROWS / 128), b256, 0, stream>>>(
      heads_int, nullptr, Wo_int, out_b, out, NROWS, EMB, EMB, slots, 4, 1, 5);

  // final fake-quant in place
  quant_k<<<1024, b256, 0, stream>>>(out, NROWS * EMB / 4, slots, 5);
}

// Round 9
// 245.247 us; speedup vs baseline: 4.6612x; 1.0100x over previous
//
#include <hip/hip_runtime.h>
#include <math.h>

#define L_SEQ 2048
#define BATCH 2
#define EMB 1024
#define NH 16
#define HDIM 64
#define F3 3072
#define NROWS 4096   // L_SEQ * BATCH
#define QBLK 128

typedef __bf16 bf16_t;
typedef short s16x8 __attribute__((ext_vector_type(8)));
typedef float f32x4 __attribute__((ext_vector_type(4)));

#define MFMA16(a, b, c) __builtin_amdgcn_mfma_f32_16x16x32_bf16(a, b, c, 0, 0, 0)

// ws slots (uint bits of fp32 absmax):
// [0]=absmax(in_w) [1]=absmax(out_w) [2]=absmax(X) [3]=max|int| of Xq Q-region
// [4]=absmax(heads) [5]=absmax(y)

__device__ __forceinline__ float u2f(unsigned u) { return __uint_as_float(u); }

__device__ __forceinline__ void gload16(const bf16_t* g, bf16_t* lds) {
  __builtin_amdgcn_global_load_lds((const __attribute__((address_space(1))) void*)g,
                                   (__attribute__((address_space(3))) void*)lds, 16, 0, 0);
}

__device__ __forceinline__ void blockmax_commit(float m, unsigned* slot) {
  #pragma unroll
  for (int o = 1; o < 64; o <<= 1) m = fmaxf(m, __shfl_xor(m, o));
  __shared__ float sm_[4];
  if ((threadIdx.x & 63) == 0) sm_[threadIdx.x >> 6] = m;
  __syncthreads();
  if (threadIdx.x == 0) {
    float mm = fmaxf(fmaxf(sm_[0], sm_[1]), fmaxf(sm_[2], sm_[3]));
    atomicMax(slot, __float_as_uint(mm));
  }
}

// absmax of in_w -> slot0 and out_w -> slot1, one launch
__global__ __launch_bounds__(256) void wabsmax_k(const float* __restrict__ wi,
                                                 const float* __restrict__ wo,
                                                 unsigned* __restrict__ slots) {
  float m0 = 0.0f, m1 = 0.0f;
  const int n0 = F3 * EMB / 4, n1 = EMB * EMB / 4;
  for (int i = blockIdx.x * blockDim.x + threadIdx.x; i < n0; i += gridDim.x * blockDim.x) {
    float4 v = ((const float4*)wi)[i];
    m0 = fmaxf(m0, fmaxf(fmaxf(fabsf(v.x), fabsf(v.y)), fmaxf(fabsf(v.z), fabsf(v.w))));
  }
  for (int i = blockIdx.x * blockDim.x + threadIdx.x; i < n1; i += gridDim.x * blockDim.x) {
    float4 v = ((const float4*)wo)[i];
    m1 = fmaxf(m1, fmaxf(fmaxf(fabsf(v.x), fabsf(v.y)), fmaxf(fabsf(v.z), fabsf(v.w))));
  }
  blockmax_commit(m0, slots + 0);
  blockmax_commit(m1, slots + 1);
}

// fused prep: quant(in_w)->Wi_int, quant(out_w)->Wo_int, split(query)->q_hi/q_lo
__global__ __launch_bounds__(256) void prep_k(const float* __restrict__ wi,
                                              const float* __restrict__ wo,
                                              const float* __restrict__ query,
                                              bf16_t* __restrict__ Wi_int,
                                              bf16_t* __restrict__ Wo_int,
                                              bf16_t* __restrict__ q_hi,
                                              bf16_t* __restrict__ q_lo,
                                              const unsigned* __restrict__ slots) {
  float s0 = fmaxf(u2f(slots[0]) / 127.0f, 1e-8f);
  float s1 = fmaxf(u2f(slots[1]) / 127.0f, 1e-8f);
  const int n0 = F3 * EMB / 4, n1 = EMB * EMB / 4, n2 = NROWS * EMB / 4;
  for (int i = blockIdx.x * blockDim.x + threadIdx.x; i < n0; i += gridDim.x * blockDim.x) {
    float4 v = ((const float4*)wi)[i];
    bf16_t o[4];
    o[0] = (bf16_t)rintf(fminf(fmaxf(v.x / s0, -128.0f), 127.0f));
    o[1] = (bf16_t)rintf(fminf(fmaxf(v.y / s0, -128.0f), 127.0f));
    o[2] = (bf16_t)rintf(fminf(fmaxf(v.z / s0, -128.0f), 127.0f));
    o[3] = (bf16_t)rintf(fminf(fmaxf(v.w / s0, -128.0f), 127.0f));
    *(uint2*)&Wi_int[(size_t)i * 4] = *(uint2*)o;
  }
  for (int i = blockIdx.x * blockDim.x + threadIdx.x; i < n1; i += gridDim.x * blockDim.x) {
    float4 v = ((const float4*)wo)[i];
    bf16_t o[4];
    o[0] = (bf16_t)rintf(fminf(fmaxf(v.x / s1, -128.0f), 127.0f));
    o[1] = (bf16_t)rintf(fminf(fmaxf(v.y / s1, -128.0f), 127.0f));
    o[2] = (bf16_t)rintf(fminf(fmaxf(v.z / s1, -128.0f), 127.0f));
    o[3] = (bf16_t)rintf(fminf(fmaxf(v.w / s1, -128.0f), 127.0f));
    *(uint2*)&Wo_int[(size_t)i * 4] = *(uint2*)o;
  }
  for (int i = blockIdx.x * blockDim.x + threadIdx.x; i < n2; i += gridDim.x * blockDim.x) {
    float4 v = ((const float4*)query)[i];
    bf16_t h[4], l[4];
    float vv[4] = {v.x, v.y, v.z, v.w};
    #pragma unroll
    for (int j = 0; j < 4; ++j) {
      h[j] = (bf16_t)vv[j];
      l[j] = (bf16_t)(vv[j] - (float)h[j]);
    }
    *(uint2*)&q_hi[(size_t)i * 4] = *(uint2*)h;
    *(uint2*)&q_lo[(size_t)i * 4] = *(uint2*)l;
  }
}

// X pass over Q+K cols (0..2047): fp32 -> int bf16, fused Q-region |int| max -> slots[3]
__global__ __launch_bounds__(256) void quantX_k(const float* __restrict__ x,
                                                bf16_t* __restrict__ y,
                                                unsigned* __restrict__ slots) {
  float s = fmaxf(u2f(slots[2]) / 127.0f, 1e-8f);
  float qm = 0.0f;
  const int n8 = NROWS * 256;   // 2048 cols / 8 per row
  for (int i = blockIdx.x * blockDim.x + threadIdx.x; i < n8; i += gridDim.x * blockDim.x) {
    int row = i >> 8, ch = i & 255;
    const float* px = x + (size_t)row * F3 + ch * 8;
    float4 v0 = *(const float4*)px;
    float4 v1 = *(const float4*)(px + 4);
    float vv[8] = {v0.x, v0.y, v0.z, v0.w, v1.x, v1.y, v1.z, v1.w};
    bf16_t o[8];
    float lm = 0.0f;
    #pragma unroll
    for (int j = 0; j < 8; ++j) {
      float q = rintf(fminf(fmaxf(vv[j] / s, -128.0f), 127.0f));
      o[j] = (bf16_t)q;
      lm = fmaxf(lm, fabsf(q));
    }
    if (ch < 128) qm = fmaxf(qm, lm);
    *(uint4*)&y[(size_t)row * F3 + ch * 8] = *(uint4*)o;
  }
  blockmax_commit(qm, slots + 3);
}

// fp32 real-valued fake-quant in place (final output)
__global__ __launch_bounds__(256) void quant_k(float* __restrict__ x, int n4,
                                               const unsigned* __restrict__ slots, int sloti) {
  float s = fmaxf(u2f(slots[sloti]) / 127.0f, 1e-8f);
  float4* x4 = (float4*)x;
  for (int i = blockIdx.x * blockDim.x + threadIdx.x; i < n4; i += gridDim.x * blockDim.x) {
    float4 v = x4[i];
    v.x = rintf(fminf(fmaxf(v.x / s, -128.0f), 127.0f)) * s;
    v.y = rintf(fminf(fmaxf(v.y / s, -128.0f), 127.0f)) * s;
    v.z = rintf(fminf(fmaxf(v.z / s, -128.0f), 127.0f)) * s;
    v.w = rintf(fminf(fmaxf(v.w / s, -128.0f), 127.0f)) * s;
    x4[i] = v;
  }
}

// fp32 -> integer-valued bf16 (heads)
__global__ __launch_bounds__(256) void quantf_k(const float* __restrict__ x,
                                                bf16_t* __restrict__ y, int n4,
                                                const unsigned* __restrict__ slots, int sloti) {
  float s = fmaxf(u2f(slots[sloti]) / 127.0f, 1e-8f);
  const float4* x4 = (const float4*)x;
  for (int i = blockIdx.x * blockDim.x + threadIdx.x; i < n4; i += gridDim.x * blockDim.x) {
    float4 v = x4[i];
    bf16_t o[4];
    o[0] = (bf16_t)rintf(fminf(fmaxf(v.x / s, -128.0f), 127.0f));
    o[1] = (bf16_t)rintf(fminf(fmaxf(v.y / s, -128.0f), 127.0f));
    o[2] = (bf16_t)rintf(fminf(fmaxf(v.z / s, -128.0f), 127.0f));
    o[3] = (bf16_t)rintf(fminf(fmaxf(v.w / s, -128.0f), 127.0f));
    *(uint2*)&y[(size_t)i * 4] = *(uint2*)o;
  }
}

// V region of X_f32 -> quant -> Vt[bh][d][token] (swizzled-LDS 64x64 transpose)
__global__ __launch_bounds__(256) void vtrans_k(const float* __restrict__ X,
                                                bf16_t* __restrict__ Vt,
                                                const unsigned* __restrict__ slots) {
  float s = fmaxf(u2f(slots[2]) / 127.0f, 1e-8f);
  __shared__ __align__(16) bf16_t tile[64][72];
  int tt = blockIdx.x, bh = blockIdx.y;
  int b = bh >> 4, h = bh & 15;
  int t = threadIdx.x;
  #pragma unroll
  for (int i = 0; i < 2; ++i) {
    int s_ = t + i * 256;
    int tok = s_ >> 3, seg = s_ & 7;
    const float* px = X + ((size_t)(tt * 64 + tok) * BATCH + b) * F3 + 2 * EMB + h * HDIM + seg * 8;
    float4 v0 = *(const float4*)px;
    float4 v1 = *(const float4*)(px + 4);
    float vv[8] = {v0.x, v0.y, v0.z, v0.w, v1.x, v1.y, v1.z, v1.w};
    bf16_t o[8];
    #pragma unroll
    for (int j = 0; j < 8; ++j)
      o[j] = (bf16_t)rintf(fminf(fmaxf(vv[j] / s, -128.0f), 127.0f));
    int segs = seg ^ (tok >> 3);
    *(uint4*)&tile[tok][segs * 8] = *(uint4*)o;
  }
  __syncthreads();
  #pragma unroll
  for (int i = 0; i < 2; ++i) {
    int s_ = t + i * 256;
    int d = s_ >> 3, tseg = s_ & 7;
    bf16_t o[8];
    #pragma unroll
    for (int e = 0; e < 8; ++e) {
      int tok = tseg * 8 + e;
      o[e] = tile[tok][(((d >> 3) ^ (tok >> 3)) << 3) | (d & 7)];
    }
    *(uint4*)&Vt[((size_t)bh * HDIM + d) * L_SEQ + tt * 64 + tseg * 8] = *(uint4*)o;
  }
}

// C[M,N] = (sum_p A_p[M,K]) @ B[N,K]^T * scale + bias[N]; bf16 in, f32 out.
// global_load_lds + 2-phase dbuf + XCD-swizzled block ids. Fused absmax -> slots[smax].
template <int NPARTS>
__global__ __launch_bounds__(256) void gemm_bt_mfma_k(const bf16_t* __restrict__ A0,
                                                      const bf16_t* __restrict__ A1,
                                                      const bf16_t* __restrict__ Bm,
                                                      const float* __restrict__ bias,
                                                      float* __restrict__ C,
                                                      int M, int N, int K,
                                                      unsigned* __restrict__ slots,
                                                      int sa, int sb, int smax) {
  __shared__ __align__(16) bf16_t sbuf[2][NPARTS + 1][128][32];
  int t = threadIdx.x;
  int w = t >> 6, l = t & 63, c15 = l & 15, g = l >> 4;
  int wr = w >> 1, wc = w & 1;
  // bijective XCD swizzle (nwg % 8 == 0 for both GEMMs)
  int nx = gridDim.x;
  int fid = blockIdx.y * nx + blockIdx.x;
  int qq = (nx * gridDim.y) >> 3;
  int swz = (fid & 7) * qq + (fid >> 3);
  int bm = (swz / nx) * 128, bn = (swz % nx) * 128;
  f32x4 acc[4][4] = {};

  auto stage = [&](int bf, int k0) {
    #pragma unroll
    for (int i = 0; i < 2; ++i) {
      int c = i * 256 + t;              // 16B-chunk id 0..511
      int row = c >> 2, sg = c & 3;
      int wb = (i * 256 + w * 64) * 8;  // wave-uniform LDS base (bf16 elems)
      gload16(&A0[(size_t)(bm + row) * K + k0 + sg * 8], &sbuf[bf][0][0][0] + wb);
      if (NPARTS == 2)
        gload16(&A1[(size_t)(bm + row) * K + k0 + sg * 8], &sbuf[bf][1][0][0] + wb);
      gload16(&Bm[(size_t)(bn + row) * K + k0 + sg * 8], &sbuf[bf][NPARTS][0][0] + wb);
    }
  };

  stage(0, 0);
  __syncthreads();
  const int nk = K / 32;
  for (int kt = 0; kt < nk; ++kt) {
    int cur = kt & 1;
    if (kt + 1 < nk) stage(cur ^ 1, (kt + 1) * 32);
    s16x8 af[NPARTS][4], bf_[4];
    #pragma unroll
    for (int rt = 0; rt < 4; ++rt) {
      af[0][rt] = *(const s16x8*)&sbuf[cur][0][wr * 64 + rt * 16 + c15][g * 8];
      if (NPARTS == 2) af[1][rt] = *(const s16x8*)&sbuf[cur][1][wr * 64 + rt * 16 + c15][g * 8];
    }
    #pragma unroll
    for (int ct = 0; ct < 4; ++ct)
      bf_[ct] = *(const s16x8*)&sbuf[cur][NPARTS][wc * 64 + ct * 16 + c15][g * 8];
    __builtin_amdgcn_s_setprio(1);
    #pragma unroll
    for (int rt = 0; rt < 4; ++rt)
      #pragma unroll
      for (int ct = 0; ct < 4; ++ct) {
        acc[rt][ct] = MFMA16(af[0][rt], bf_[ct], acc[rt][ct]);
        if (NPARTS == 2) acc[rt][ct] = MFMA16(af[1][rt], bf_[ct], acc[rt][ct]);
      }
    __builtin_amdgcn_s_setprio(0);
    __syncthreads();
  }

  float s = 1.0f;
  if (sa >= 0) s *= fmaxf(u2f(slots[sa]) / 127.0f, 1e-8f);
  if (sb >= 0) s *= fmaxf(u2f(slots[sb]) / 127.0f, 1e-8f);
  float vmax = 0.0f;
  #pragma unroll
  for (int rt = 0; rt < 4; ++rt)
    #pragma unroll
    for (int r = 0; r < 4; ++r) {
      int row = bm + wr * 64 + rt * 16 + 4 * g + r;
      #pragma unroll
      for (int ct = 0; ct < 4; ++ct) {
        int col = bn + wc * 64 + ct * 16 + c15;
        float o = acc[rt][ct][r] * s + bias[col];
        vmax = fmaxf(vmax, fabsf(o));
        C[(size_t)row * N + col] = o;
      }
    }
  if (smax >= 0) blockmax_commit(vmax, slots + smax);
}

// Flash attention, swapped-operand MFMA, tau-permuted K staging (P fully in registers).
// QBLK=128: 4 waves x 2 q-tiles (32 q-rows/wave); K/V frags reused in registers across
// tiles. Grid (x=bh=32, y=qb=16): linear bid % 8 == bh % 8 -> all q-blocks of a head on
// one XCD, K/V panel (512KB x 4 heads = 2MB) L2-resident.
__global__ __launch_bounds__(256) void attn_mfma_k(const bf16_t* __restrict__ X,
                                                   const bf16_t* __restrict__ Vt,
                                                   float* __restrict__ heads,
                                                   unsigned* __restrict__ slots) {
  int bh = blockIdx.x, qb = blockIdx.y;
  int b = bh >> 4, h = bh & 15;
  int t = threadIdx.x;
  int w = t >> 6, l = t & 63, c15 = l & 15, g = l >> 4;

  float s_x = fmaxf(u2f(slots[2]) / 127.0f, 1e-8f);
  float s_q = fmaxf((u2f(slots[3]) * s_x) * 0.125f / 127.0f, 1e-8f);
  const float LOG2E = 1.4426950408889634f;
  float qsl2 = s_q * s_x * LOG2E;   // raw int-score -> log2 domain

  __shared__ __align__(16) union SmKV {
    struct { bf16_t K[2][64][64]; bf16_t V[2][64][64]; } kv;   // 32768 B
    float Ot[4][16][69];                                       // epilogue overlay
  } sm;

  // Q frags (2 tiles) with fused requant
  s16x8 qf0[2], qf1[2];
  #pragma unroll
  for (int tile = 0; tile < 2; ++tile) {
    int qtok = qb * QBLK + w * 32 + tile * 16 + c15;
    const bf16_t* qbase = X + ((size_t)qtok * BATCH + b) * F3 + h * HDIM;
    bf16_t qt[8];
    #pragma unroll
    for (int half = 0; half < 2; ++half) {
      *(uint4*)qt = *(const uint4*)(qbase + half * 32 + g * 8);
      #pragma unroll
      for (int j = 0; j < 8; ++j) {
        float q = ((float)qt[j] * s_x) * 0.125f;
        qt[j] = (bf16_t)rintf(fminf(fmaxf(q / s_q, -128.0f), 127.0f));
      }
      if (half == 0) qf0[tile] = *(s16x8*)qt; else qf1[tile] = *(s16x8*)qt;
    }
  }

  const size_t tokstride = (size_t)BATCH * F3;
  const bf16_t* kbase = X + (size_t)b * F3 + EMB + h * HDIM;
  const bf16_t* vbase = Vt + (size_t)bh * HDIM * L_SEQ;

  // stage tile kt into buffer buf: linear LDS dest, tau+XOR-swizzle baked into global src
  auto stage = [&](int buf, int kt) {
    #pragma unroll
    for (int i = 0; i < 2; ++i) {
      int c = i * 256 + t;              // chunk 0..511 of K[buf]
      int a = c >> 3, blk = c & 7;
      int kap = (a & 0x20) | ((a & 0x10) >> 2) | ((a & 0x0C) << 1) | (a & 3);
      gload16(kbase + (size_t)(kt * 64 + kap) * tokstride + (blk ^ (a & 7)) * 8,
              &sm.kv.K[buf][0][0] + (i * 256 + w * 64) * 8);
    }
    #pragma unroll
    for (int i = 0; i < 2; ++i) {
      int c = i * 256 + t;              // chunk 0..511 of V[buf]
      int d = c >> 3, blk = c & 7;
      gload16(vbase + (size_t)d * L_SEQ + kt * 64 + (blk ^ (d & 7)) * 8,
              &sm.kv.V[buf][0][0] + (i * 256 + w * 64) * 8);
    }
  };

  f32x4 acc_o[2][4] = {};
  float m_prev[2] = {-INFINITY, -INFINITY};
  float lsum[2] = {0.0f, 0.0f};
  int sw = c15 & 7;                     // read swizzle (row&7 == c15&7 for all frag rows)

  stage(0, 0);
  __syncthreads();

  const int NT = L_SEQ / 64;
  int cur = 0;
  for (int kt = 0; kt < NT; ++kt) {
    if (kt + 1 < NT) stage(cur ^ 1, kt + 1);

    // QK^T swapped: A=K (rows = tau-permuted tokens), B=Q (cols=q); K frags reused x2
    f32x4 accs[2][4] = {};
    __builtin_amdgcn_s_setprio(1);
    #pragma unroll
    for (int ct = 0; ct < 4; ++ct) {
      const bf16_t* krow = &sm.kv.K[cur][ct * 16 + c15][0];
      s16x8 kf0 = *(const s16x8*)(krow + (g ^ sw) * 8);
      s16x8 kf1 = *(const s16x8*)(krow + ((g | 4) ^ sw) * 8);
      accs[0][ct] = MFMA16(kf0, qf0[0], accs[0][ct]);
      accs[0][ct] = MFMA16(kf1, qf1[0], accs[0][ct]);
      accs[1][ct] = MFMA16(kf0, qf0[1], accs[1][ct]);
      accs[1][ct] = MFMA16(kf1, qf1[1], accs[1][ct]);
    }
    __builtin_amdgcn_s_setprio(0);

    // per-tile in-register softmax (q = tile*16 + c15; lane holds 16 of 64 scores)
    s16x8 pfh0[2], pfh1[2], pfl0[2], pfl1[2];
    #pragma unroll
    for (int tile = 0; tile < 2; ++tile) {
      float pm = accs[tile][0][0];
      #pragma unroll
      for (int ct = 0; ct < 4; ++ct)
        #pragma unroll
        for (int r = 0; r < 4; ++r) pm = fmaxf(pm, accs[tile][ct][r]);
      pm = fmaxf(pm, __shfl_xor(pm, 16));
      pm = fmaxf(pm, __shfl_xor(pm, 32));
      float mnew = fmaxf(m_prev[tile], pm);
      float f_ = __builtin_amdgcn_exp2f((m_prev[tile] - mnew) * qsl2);
      float mq = mnew * qsl2;
      float ps = 0.0f;
      bf16_t hh[2][8], ll[2][8];
      #pragma unroll
      for (int ct = 0; ct < 4; ++ct) {
        float p[4];
        #pragma unroll
        for (int r = 0; r < 4; ++r)
          p[r] = __builtin_amdgcn_exp2f(fmaf(accs[tile][ct][r], qsl2, -mq));
        ps += (p[0] + p[1]) + (p[2] + p[3]);
        #pragma unroll
        for (int r = 0; r < 4; ++r) {
          bf16_t hi = (bf16_t)p[r];
          hh[ct >> 1][(ct & 1) * 4 + r] = hi;
          ll[ct >> 1][(ct & 1) * 4 + r] = (bf16_t)(p[r] - (float)hi);
        }
      }
      lsum[tile] = lsum[tile] * f_ + ps;
      m_prev[tile] = mnew;
      if (!__all(f_ == 1.0f)) {
        #pragma unroll
        for (int dt = 0; dt < 4; ++dt)
          #pragma unroll
          for (int r = 0; r < 4; ++r) acc_o[tile][dt][r] *= f_;
      }
      pfh0[tile] = *(s16x8*)hh[0]; pfh1[tile] = *(s16x8*)hh[1];
      pfl0[tile] = *(s16x8*)ll[0]; pfl1[tile] = *(s16x8*)ll[1];
    }

    // PV swapped: A=V^T, B=P; V frags reused across the 2 q-tiles
    __builtin_amdgcn_s_setprio(1);
    #pragma unroll
    for (int dt = 0; dt < 4; ++dt) {
      const bf16_t* vrow = &sm.kv.V[cur][dt * 16 + c15][0];
      s16x8 vf0 = *(const s16x8*)(vrow + (g ^ sw) * 8);
      s16x8 vf1 = *(const s16x8*)(vrow + ((g | 4) ^ sw) * 8);
      #pragma unroll
      for (int tile = 0; tile < 2; ++tile) {
        acc_o[tile][dt] = MFMA16(vf0, pfh0[tile], acc_o[tile][dt]);
        acc_o[tile][dt] = MFMA16(vf1, pfh1[tile], acc_o[tile][dt]);
        acc_o[tile][dt] = MFMA16(vf0, pfl0[tile], acc_o[tile][dt]);
        acc_o[tile][dt] = MFMA16(vf1, pfl1[tile], acc_o[tile][dt]);
      }
    }
    __builtin_amdgcn_s_setprio(0);

    __syncthreads();   // drains gload_lds (vmcnt) -> next buffer staged; cur reads done
    cur ^= 1;
  }

  // epilogue per tile: lsum finalize, O^T -> Ot[w] (same-wave LDS, in-order DS pipe)
  float hm = 0.0f;
  int ql = l >> 2, cs = l & 3;
  #pragma unroll
  for (int tile = 0; tile < 2; ++tile) {
    float l2 = lsum[tile];
    l2 += __shfl_xor(l2, 16);
    l2 += __shfl_xor(l2, 32);
    float inv = s_x / l2;
    #pragma unroll
    for (int dt = 0; dt < 4; ++dt)
      #pragma unroll
      for (int r = 0; r < 4; ++r) {
        float o = acc_o[tile][dt][r] * inv;
        hm = fmaxf(hm, fabsf(o));
        sm.Ot[w][c15][dt * 16 + 4 * g + r] = o;
      }
    #pragma unroll
    for (int j = 0; j < 4; ++j) {
      int cch = cs + 4 * j;
      float4 v = *(const float4*)&sm.Ot[w][ql][cch * 4];
      int tok = qb * QBLK + w * 32 + tile * 16 + ql;
      *(float4*)&heads[((size_t)tok * BATCH + b) * EMB + h * HDIM + cch * 4] = v;
    }
  }
  blockmax_commit(hm, slots + 4);
}

extern "C" void kernel_launch(void* const* d_in, const int* in_sizes, int n_in,
                              void* d_out, int out_size, void* d_ws, size_t ws_size,
                              hipStream_t stream) {
  (void)in_sizes; (void)n_in; (void)out_size; (void)ws_size;
  const float* query = (const float*)d_in[0];
  const float* in_w  = (const float*)d_in[3];
  const float* in_b  = (const float*)d_in[4];
  const float* out_w = (const float*)d_in[5];
  const float* out_b = (const float*)d_in[6];
  float* out = (float*)d_out;

  unsigned* slots = (unsigned*)d_ws;
  char* p = (char*)d_ws + 256;
  bf16_t* q_hi   = (bf16_t*)p;                  p += (size_t)NROWS * EMB * 2;   // 8 MB
  bf16_t* q_lo   = (bf16_t*)p;                  p += (size_t)NROWS * EMB * 2;   // 8 MB
  bf16_t* Wi_int = (bf16_t*)p;                  p += (size_t)F3 * EMB * 2;      // 6 MB
  bf16_t* Wo_int = (bf16_t*)p;                  p += (size_t)EMB * EMB * 2;     // 2 MB
  float*  X_f32  = (float*)p;                   p += (size_t)NROWS * F3 * 4;    // 48 MB
  bf16_t* X_int  = (bf16_t*)p;                                                  // 24 MB
  bf16_t* Vt     = q_hi;               // q_hi dead after GEMM1; reuse (8 MB)
  bf16_t* heads_int = (bf16_t*)X_f32;  // X_f32 dead after quantX+vtrans
  float*  heads_f32 = out;             // d_out doubles as heads staging

  hipMemsetAsync(d_ws, 0, 256, stream);

  dim3 b256(256);
  // weight absmax (one launch), then fused quant-weights + query split
  wabsmax_k<<<768, b256, 0, stream>>>(in_w, out_w, slots);
  prep_k<<<1024, b256, 0, stream>>>(in_w, out_w, query, Wi_int, Wo_int, q_hi, q_lo, slots);

  // GEMM1: X = (q_hi+q_lo) @ Wi_int^T * s_wi + in_b ; fused absmax(X) -> slot2
  gemm_bt_mfma_k<2><<<dim3(F3 / 128, NROWS / 128), b256, 0, stream>>>(
      q_hi, q_lo, Wi_int, in_b, X_f32, NROWS, F3, EMB, slots, -1, 0, 2);

  // X Q/K cols -> int bf16, fused Q-region |int| max -> slot3
  quantX_k<<<2048, b256, 0, stream>>>(X_f32, X_int, slots);

  // V region: quant + transpose from X_f32 (into dead q_hi region)
  vtrans_k<<<dim3(L_SEQ / 64, BATCH * NH), b256, 0, stream>>>(X_f32, Vt, slots);

  // attention (q requant fused) -> heads_f32 (= d_out), fused absmax(heads) -> slot4
  attn_mfma_k<<<dim3(BATCH * NH, L_SEQ / QBLK), b256, 0, stream>>>(X_int, Vt, heads_f32, slots);

  // heads -> int bf16
  quantf_k<<<1024, b256, 0, stream>>>(heads_f32, heads_int, NROWS * EMB / 4, slots, 4);

  // GEMM2: y = heads_int @ Wo_int^T * (s_h*s_wo) + out_b ; fused absmax(y) -> slot5
  gemm_bt_mfma_k<1><<<dim3(EMB / 128, NROWS / 128), b256, 0, stream>>>(
      heads_int, nullptr, Wo_int, out_b, out, NROWS, EMB, EMB, slots, 4, 1, 5);

  // final fake-quant in place
  quant_k<<<1024, b256, 0, stream>>>(out, NROWS * EMB / 4, slots, 5);
}